// Round 2
// baseline (932.768 us; speedup 1.0000x reference)
//
#include <hip/hip_runtime.h>
#include <hip/hip_bf16.h>

// GAT 2-layer + linear head. All fp32.
// N=50000, E=400000 (+N self loops), IN_DIM=128, HEADS=3, HID=64 (HC=192), CLASSES=40.

#define NNODES 50000
#define NEDGES 400000
#define HC 192
#define NHEADS 3
#define HIDC 64
#define NCLS 40

__device__ __forceinline__ float lrelu(float a) { return a > 0.f ? a : 0.2f * a; }

// ---------------- CSR build ----------------

__global__ void hist_kernel(const int* __restrict__ ei, int* __restrict__ deg,
                            int E_, int n) {
    int e = blockIdx.x * blockDim.x + threadIdx.x;
    int ET = E_ + n;
    if (e >= ET) return;
    int d = (e < E_) ? ei[E_ + e] : (e - E_);
    atomicAdd(&deg[d], 1);
}

__global__ __launch_bounds__(1024) void scan_kernel(const int* __restrict__ deg,
                                                    int* __restrict__ rowp, int n) {
    __shared__ int sums[1024];
    int tid = threadIdx.x;
    int per = (n + 1023) >> 10;
    int begin = tid * per;
    int end = begin + per; if (end > n) end = n;
    int s = 0;
    for (int i = begin; i < end && i < n; ++i) s += deg[i];
    sums[tid] = s;
    __syncthreads();
    for (int off = 1; off < 1024; off <<= 1) {
        int v = (tid >= off) ? sums[tid - off] : 0;
        __syncthreads();
        sums[tid] += v;
        __syncthreads();
    }
    int run = (tid == 0) ? 0 : sums[tid - 1];
    for (int i = begin; i < end && i < n; ++i) {
        rowp[i] = run;
        run += deg[i];
    }
    if (tid == 1023) rowp[n] = sums[1023];
}

__global__ void scatter_kernel(const int* __restrict__ ei, const int* __restrict__ rowp,
                               int* __restrict__ cursor, int* __restrict__ esrc,
                               int E_, int n) {
    int e = blockIdx.x * blockDim.x + threadIdx.x;
    int ET = E_ + n;
    if (e >= ET) return;
    int s, d;
    if (e < E_) { s = ei[e]; d = ei[E_ + e]; }
    else        { s = e - E_; d = s; }
    int pos = atomicAdd(&cursor[d], 1);
    esrc[rowp[d] + pos] = s;
}

// ---------------- GEMM: C[n,M] = X[n,K] @ W[M,K]^T (+bias) ----------------
// BM=256, BN=64, BK=16, 256 threads, per-thread 8x8, float4 LDS reads.

template <int K, int M, bool ADD_BIAS>
__global__ __launch_bounds__(256, 4) void gemm_xwt(const float* __restrict__ X,
                                                   const float* __restrict__ W,
                                                   const float* __restrict__ bias,
                                                   float* __restrict__ C, int n) {
    const int BM = 256, BN = 64, BK = 16;
    __shared__ float Xs[BK][BM + 4];
    __shared__ float Ws[BK][BN + 4];
    int bm = blockIdx.x * BM;
    int bn = blockIdx.y * BN;
    int tid = threadIdx.x;
    int tx = tid & 7;    // 8 col groups of 8
    int ty = tid >> 3;   // 32 row groups of 8
    float acc[8][8] = {};

    for (int k0 = 0; k0 < K; k0 += BK) {
        // X tile: 256x16 floats = 1024 float4, 4 per thread
#pragma unroll
        for (int t = 0; t < 4; ++t) {
            int q = tid + t * 256;
            int row = q >> 2;
            int ks = (q & 3) * 4;
            int grow = bm + row;
            float4 v = make_float4(0.f, 0.f, 0.f, 0.f);
            if (grow < n) v = *(const float4*)(X + (size_t)grow * K + k0 + ks);
            Xs[ks + 0][row] = v.x; Xs[ks + 1][row] = v.y;
            Xs[ks + 2][row] = v.z; Xs[ks + 3][row] = v.w;
        }
        // W tile: 64x16 floats = 256 float4, 1 per thread
        {
            int rowm = tid >> 2;
            int ks = (tid & 3) * 4;
            int gm = bn + rowm;
            float4 v = make_float4(0.f, 0.f, 0.f, 0.f);
            if (gm < M) v = *(const float4*)(W + (size_t)gm * K + k0 + ks);
            Ws[ks + 0][rowm] = v.x; Ws[ks + 1][rowm] = v.y;
            Ws[ks + 2][rowm] = v.z; Ws[ks + 3][rowm] = v.w;
        }
        __syncthreads();
#pragma unroll
        for (int kk = 0; kk < BK; ++kk) {
            float4 xa = *(const float4*)&Xs[kk][ty * 8];
            float4 xb = *(const float4*)&Xs[kk][ty * 8 + 4];
            float4 wa = *(const float4*)&Ws[kk][tx * 8];
            float4 wb = *(const float4*)&Ws[kk][tx * 8 + 4];
            float xr[8] = {xa.x, xa.y, xa.z, xa.w, xb.x, xb.y, xb.z, xb.w};
            float wr[8] = {wa.x, wa.y, wa.z, wa.w, wb.x, wb.y, wb.z, wb.w};
#pragma unroll
            for (int i = 0; i < 8; ++i)
#pragma unroll
                for (int j = 0; j < 8; ++j) acc[i][j] += xr[i] * wr[j];
        }
        __syncthreads();
    }
#pragma unroll
    for (int i = 0; i < 8; ++i) {
        int grow = bm + ty * 8 + i;
        if (grow >= n) continue;
#pragma unroll
        for (int jh = 0; jh < 2; ++jh) {
            int gcol = bn + tx * 8 + jh * 4;
            if (gcol + 3 < M) {
                float4 v;
                v.x = acc[i][jh * 4 + 0]; v.y = acc[i][jh * 4 + 1];
                v.z = acc[i][jh * 4 + 2]; v.w = acc[i][jh * 4 + 3];
                if (ADD_BIAS) {
                    v.x += bias[gcol + 0]; v.y += bias[gcol + 1];
                    v.z += bias[gcol + 2]; v.w += bias[gcol + 3];
                }
                *(float4*)(C + (size_t)grow * M + gcol) = v;
            } else {
#pragma unroll
                for (int j = 0; j < 4; ++j) {
                    int gc = gcol + j;
                    if (gc < M) {
                        float v = acc[i][jh * 4 + j];
                        if (ADD_BIAS) v += bias[gc];
                        C[(size_t)grow * M + gc] = v;
                    }
                }
            }
        }
    }
}

// ---------------- attention projections: al/ar [n,3] ----------------

__global__ __launch_bounds__(256) void attproj_kernel(const float* __restrict__ A,
                                                      const float* __restrict__ attl,
                                                      const float* __restrict__ attr,
                                                      float* __restrict__ al,
                                                      float* __restrict__ ar, int n) {
    int wave = threadIdx.x >> 6;
    int lane = threadIdx.x & 63;
    int node = blockIdx.x * 4 + wave;
    if (node >= n) return;
#pragma unroll
    for (int h = 0; h < NHEADS; ++h) {
        float v = A[(size_t)node * HC + h * HIDC + lane];
        float pl = v * attl[h * HIDC + lane];
        float pr = v * attr[h * HIDC + lane];
#pragma unroll
        for (int off = 32; off; off >>= 1) {
            pl += __shfl_xor(pl, off);
            pr += __shfl_xor(pr, off);
        }
        if (lane == 0) {
            al[node * NHEADS + h] = pl;
            ar[node * NHEADS + h] = pr;
        }
    }
}

// ---------------- edge softmax weights (normalized), wave per node ----------------

__global__ __launch_bounds__(256) void weight_kernel(const float* __restrict__ al,
                                                     const float* __restrict__ ar,
                                                     const int* __restrict__ rowp,
                                                     const int* __restrict__ esrc,
                                                     float* __restrict__ wgt, int n) {
    int node = blockIdx.x * 4 + (threadIdx.x >> 6);
    int lane = threadIdx.x & 63;
    if (node >= n) return;
    int e0 = rowp[node], e1 = rowp[node + 1];
    float ar0 = ar[node * 3 + 0], ar1 = ar[node * 3 + 1], ar2 = ar[node * 3 + 2];
    // pass 1: max
    float m0 = -1e30f, m1 = -1e30f, m2 = -1e30f;
    for (int p = e0 + lane; p < e1; p += 64) {
        int s = esrc[p];
        m0 = fmaxf(m0, lrelu(al[s * 3 + 0] + ar0));
        m1 = fmaxf(m1, lrelu(al[s * 3 + 1] + ar1));
        m2 = fmaxf(m2, lrelu(al[s * 3 + 2] + ar2));
    }
#pragma unroll
    for (int off = 32; off; off >>= 1) {
        m0 = fmaxf(m0, __shfl_xor(m0, off));
        m1 = fmaxf(m1, __shfl_xor(m1, off));
        m2 = fmaxf(m2, __shfl_xor(m2, off));
    }
    // pass 2: denom
    float s0 = 0.f, s1 = 0.f, s2 = 0.f;
    for (int p = e0 + lane; p < e1; p += 64) {
        int s = esrc[p];
        s0 += __expf(lrelu(al[s * 3 + 0] + ar0) - m0);
        s1 += __expf(lrelu(al[s * 3 + 1] + ar1) - m1);
        s2 += __expf(lrelu(al[s * 3 + 2] + ar2) - m2);
    }
#pragma unroll
    for (int off = 32; off; off >>= 1) {
        s0 += __shfl_xor(s0, off);
        s1 += __shfl_xor(s1, off);
        s2 += __shfl_xor(s2, off);
    }
    float r0 = 1.f / (s0 + 1e-16f), r1 = 1.f / (s1 + 1e-16f), r2 = 1.f / (s2 + 1e-16f);
    // pass 3: write normalized weights
    for (int p = e0 + lane; p < e1; p += 64) {
        int s = esrc[p];
        wgt[p * 3 + 0] = __expf(lrelu(al[s * 3 + 0] + ar0) - m0) * r0;
        wgt[p * 3 + 1] = __expf(lrelu(al[s * 3 + 1] + ar1) - m1) * r1;
        wgt[p * 3 + 2] = __expf(lrelu(al[s * 3 + 2] + ar2) - m2) * r2;
    }
}

// ---------------- gather: block per node, wave per head ----------------

template <bool RELU>
__global__ __launch_bounds__(192) void gather_kernel(const float* __restrict__ hfeat,
                                                     const float* __restrict__ wgt,
                                                     const int* __restrict__ rowp,
                                                     const int* __restrict__ esrc,
                                                     const float* __restrict__ bias,
                                                     float* __restrict__ out, int n) {
    int node = blockIdx.x;
    int head = threadIdx.x >> 6;
    int lane = threadIdx.x & 63;
    int e0 = rowp[node], e1 = rowp[node + 1];
    const float* base = hfeat + head * HIDC + lane;
    float acc = 0.f;
    int e = e0;
    // 4-deep batched for ILP (independent gather loads in flight)
    for (; e + 4 <= e1; e += 4) {
        int s0 = esrc[e + 0], s1 = esrc[e + 1], s2 = esrc[e + 2], s3 = esrc[e + 3];
        float w0 = wgt[(e + 0) * 3 + head];
        float w1 = wgt[(e + 1) * 3 + head];
        float w2 = wgt[(e + 2) * 3 + head];
        float w3 = wgt[(e + 3) * 3 + head];
        float h0 = base[(size_t)s0 * HC];
        float h1 = base[(size_t)s1 * HC];
        float h2 = base[(size_t)s2 * HC];
        float h3 = base[(size_t)s3 * HC];
        acc += w0 * h0 + w1 * h1 + w2 * h2 + w3 * h3;
    }
    for (; e < e1; ++e) {
        int s = esrc[e];
        acc += wgt[e * 3 + head] * base[(size_t)s * HC];
    }
    float v = acc + bias[head * HIDC + lane];
    if (RELU) v = fmaxf(v, 0.f);
    out[(size_t)node * HC + head * HIDC + lane] = v;
}

// ---------------- launch ----------------

extern "C" void kernel_launch(void* const* d_in, const int* in_sizes, int n_in,
                              void* d_out, int out_size, void* d_ws, size_t ws_size,
                              hipStream_t stream) {
    const float* x     = (const float*)d_in[0];
    const int*   ei    = (const int*)d_in[1];   // [2,E] int
    const float* W1    = (const float*)d_in[2];
    const float* attl1 = (const float*)d_in[3];
    const float* attr1 = (const float*)d_in[4];
    const float* b1    = (const float*)d_in[5];
    const float* W2    = (const float*)d_in[6];
    const float* attl2 = (const float*)d_in[7];
    const float* attr2 = (const float*)d_in[8];
    const float* b2    = (const float*)d_in[9];
    const float* Wo    = (const float*)d_in[10];
    const float* bo    = (const float*)d_in[11];
    float* outp = (float*)d_out;

    const int n = NNODES;
    const int E_ = NEDGES;
    const int ET = E_ + n;

    char* ws = (char*)d_ws;
    size_t off = 0;
    auto take = [&](size_t bytes) {
        size_t p = off;
        off += (bytes + 255) & ~(size_t)255;
        return p;
    };
    float* A    = (float*)(ws + take((size_t)n * HC * 4));
    float* B    = (float*)(ws + take((size_t)n * HC * 4));
    float* al   = (float*)(ws + take((size_t)n * 3 * 4));
    float* ar   = (float*)(ws + take((size_t)n * 3 * 4));
    int* rowp   = (int*)(ws + take((size_t)(n + 1) * 4));
    int* deg    = (int*)(ws + take((size_t)n * 4));
    int* cursor = (int*)(ws + take((size_t)n * 4));
    int* esrc   = (int*)(ws + take((size_t)ET * 4));
    (void)ws_size;
    // normalized edge weights live in d_out (5.4 MB < 8 MB); head GEMM
    // overwrites every element of d_out afterwards, so final contents are clean.
    float* wgt = (float*)d_out;

    hipMemsetAsync(deg, 0, (size_t)n * 4, stream);
    hipMemsetAsync(cursor, 0, (size_t)n * 4, stream);

    int eb = 256;
    int eg = (ET + eb - 1) / eb;
    hist_kernel<<<eg, eb, 0, stream>>>(ei, deg, E_, n);
    scan_kernel<<<1, 1024, 0, stream>>>(deg, rowp, n);
    scatter_kernel<<<eg, eb, 0, stream>>>(ei, rowp, cursor, esrc, E_, n);

    dim3 g1((n + 255) / 256, HC / 64);
    dim3 go((n + 255) / 256, 1);
    int nodeg4 = (n + 3) / 4;

    // layer 1
    gemm_xwt<128, HC, false><<<g1, 256, 0, stream>>>(x, W1, nullptr, A, n);
    attproj_kernel<<<nodeg4, 256, 0, stream>>>(A, attl1, attr1, al, ar, n);
    weight_kernel<<<nodeg4, 256, 0, stream>>>(al, ar, rowp, esrc, wgt, n);
    gather_kernel<true><<<n, 192, 0, stream>>>(A, wgt, rowp, esrc, b1, B, n);
    // layer 2
    gemm_xwt<HC, HC, false><<<g1, 256, 0, stream>>>(B, W2, nullptr, A, n);
    attproj_kernel<<<nodeg4, 256, 0, stream>>>(A, attl2, attr2, al, ar, n);
    weight_kernel<<<nodeg4, 256, 0, stream>>>(al, ar, rowp, esrc, wgt, n);
    gather_kernel<true><<<n, 192, 0, stream>>>(A, wgt, rowp, esrc, b2, B, n);
    // output head
    gemm_xwt<HC, NCLS, true><<<go, 256, 0, stream>>>(B, Wo, bo, outp, n);
}

// Round 3
// 508.612 us; speedup vs baseline: 1.8339x; 1.8339x over previous
//
#include <hip/hip_runtime.h>
#include <hip/hip_bf16.h>

// GAT 2-layer + linear head. All fp32.
// N=50000, E=400000 (+N self loops), IN_DIM=128, HEADS=3, HID=64 (HC=192), CLASSES=40.

#define NNODES 50000
#define NEDGES 400000
#define HC 192
#define NHEADS 3
#define HIDC 64
#define NCLS 40

__device__ __forceinline__ float lrelu(float a) { return a > 0.f ? a : 0.2f * a; }

// ---------------- CSR build ----------------

__global__ void hist_kernel(const int* __restrict__ ei, int* __restrict__ deg,
                            int E_, int n) {
    int e = blockIdx.x * blockDim.x + threadIdx.x;
    int ET = E_ + n;
    if (e >= ET) return;
    int d = (e < E_) ? ei[E_ + e] : (e - E_);
    atomicAdd(&deg[d], 1);
}

__global__ __launch_bounds__(1024) void scan_kernel(const int* __restrict__ deg,
                                                    int* __restrict__ rowp, int n) {
    __shared__ int sums[1024];
    int tid = threadIdx.x;
    int per = (n + 1023) >> 10;
    int begin = tid * per;
    int end = begin + per; if (end > n) end = n;
    int s = 0;
    for (int i = begin; i < end && i < n; ++i) s += deg[i];
    sums[tid] = s;
    __syncthreads();
    for (int off = 1; off < 1024; off <<= 1) {
        int v = (tid >= off) ? sums[tid - off] : 0;
        __syncthreads();
        sums[tid] += v;
        __syncthreads();
    }
    int run = (tid == 0) ? 0 : sums[tid - 1];
    for (int i = begin; i < end && i < n; ++i) {
        rowp[i] = run;
        run += deg[i];
    }
    if (tid == 1023) rowp[n] = sums[1023];
}

__global__ void scatter_kernel(const int* __restrict__ ei, const int* __restrict__ rowp,
                               int* __restrict__ cursor, int* __restrict__ esrc,
                               int E_, int n) {
    int e = blockIdx.x * blockDim.x + threadIdx.x;
    int ET = E_ + n;
    if (e >= ET) return;
    int s, d;
    if (e < E_) { s = ei[e]; d = ei[E_ + e]; }
    else        { s = e - E_; d = s; }
    int pos = atomicAdd(&cursor[d], 1);
    esrc[rowp[d] + pos] = s;
}

// ---------------- GEMM: C[n,M] = X[n,K] @ W[M,K]^T (+bias) ----------------
// BM=256, BN=64, BK=16, 256 threads, per-thread 8x8, float4 LDS reads.
// NOTE: launch_bounds min-waves MUST stay <=2: the 8x8 accumulator needs
// ~110 VGPRs; forcing 4 waves/EU caps at 128->spill (R2: 800MB scratch traffic).

template <int K, int M, bool ADD_BIAS>
__global__ __launch_bounds__(256, 2) void gemm_xwt(const float* __restrict__ X,
                                                   const float* __restrict__ W,
                                                   const float* __restrict__ bias,
                                                   float* __restrict__ C, int n) {
    const int BM = 256, BN = 64, BK = 16;
    __shared__ float Xs[BK][BM + 4];
    __shared__ float Ws[BK][BN + 4];
    int bm = blockIdx.x * BM;
    int bn = blockIdx.y * BN;
    int tid = threadIdx.x;
    int tx = tid & 7;    // 8 col groups of 8
    int ty = tid >> 3;   // 32 row groups of 8
    float acc[8][8] = {};

    for (int k0 = 0; k0 < K; k0 += BK) {
        // X tile: 256x16 floats = 1024 float4, 4 per thread
#pragma unroll
        for (int t = 0; t < 4; ++t) {
            int q = tid + t * 256;
            int row = q >> 2;
            int ks = (q & 3) * 4;
            int grow = bm + row;
            float4 v = make_float4(0.f, 0.f, 0.f, 0.f);
            if (grow < n) v = *(const float4*)(X + (size_t)grow * K + k0 + ks);
            Xs[ks + 0][row] = v.x; Xs[ks + 1][row] = v.y;
            Xs[ks + 2][row] = v.z; Xs[ks + 3][row] = v.w;
        }
        // W tile: 64x16 floats = 256 float4, 1 per thread
        {
            int rowm = tid >> 2;
            int ks = (tid & 3) * 4;
            int gm = bn + rowm;
            float4 v = make_float4(0.f, 0.f, 0.f, 0.f);
            if (gm < M) v = *(const float4*)(W + (size_t)gm * K + k0 + ks);
            Ws[ks + 0][rowm] = v.x; Ws[ks + 1][rowm] = v.y;
            Ws[ks + 2][rowm] = v.z; Ws[ks + 3][rowm] = v.w;
        }
        __syncthreads();
#pragma unroll
        for (int kk = 0; kk < BK; ++kk) {
            float4 xa = *(const float4*)&Xs[kk][ty * 8];
            float4 xb = *(const float4*)&Xs[kk][ty * 8 + 4];
            float4 wa = *(const float4*)&Ws[kk][tx * 8];
            float4 wb = *(const float4*)&Ws[kk][tx * 8 + 4];
            float xr[8] = {xa.x, xa.y, xa.z, xa.w, xb.x, xb.y, xb.z, xb.w};
            float wr[8] = {wa.x, wa.y, wa.z, wa.w, wb.x, wb.y, wb.z, wb.w};
#pragma unroll
            for (int i = 0; i < 8; ++i)
#pragma unroll
                for (int j = 0; j < 8; ++j) acc[i][j] += xr[i] * wr[j];
        }
        __syncthreads();
    }
#pragma unroll
    for (int i = 0; i < 8; ++i) {
        int grow = bm + ty * 8 + i;
        if (grow >= n) continue;
#pragma unroll
        for (int jh = 0; jh < 2; ++jh) {
            int gcol = bn + tx * 8 + jh * 4;
            if (gcol + 3 < M) {
                float4 v;
                v.x = acc[i][jh * 4 + 0]; v.y = acc[i][jh * 4 + 1];
                v.z = acc[i][jh * 4 + 2]; v.w = acc[i][jh * 4 + 3];
                if (ADD_BIAS) {
                    v.x += bias[gcol + 0]; v.y += bias[gcol + 1];
                    v.z += bias[gcol + 2]; v.w += bias[gcol + 3];
                }
                *(float4*)(C + (size_t)grow * M + gcol) = v;
            } else {
#pragma unroll
                for (int j = 0; j < 4; ++j) {
                    int gc = gcol + j;
                    if (gc < M) {
                        float v = acc[i][jh * 4 + j];
                        if (ADD_BIAS) v += bias[gc];
                        C[(size_t)grow * M + gc] = v;
                    }
                }
            }
        }
    }
}

// ---------------- attention projections: al/ar [n,3] ----------------

__global__ __launch_bounds__(256) void attproj_kernel(const float* __restrict__ A,
                                                      const float* __restrict__ attl,
                                                      const float* __restrict__ attr,
                                                      float* __restrict__ al,
                                                      float* __restrict__ ar, int n) {
    int wave = threadIdx.x >> 6;
    int lane = threadIdx.x & 63;
    int node = blockIdx.x * 4 + wave;
    if (node >= n) return;
#pragma unroll
    for (int h = 0; h < NHEADS; ++h) {
        float v = A[(size_t)node * HC + h * HIDC + lane];
        float pl = v * attl[h * HIDC + lane];
        float pr = v * attr[h * HIDC + lane];
#pragma unroll
        for (int off = 32; off; off >>= 1) {
            pl += __shfl_xor(pl, off);
            pr += __shfl_xor(pr, off);
        }
        if (lane == 0) {
            al[node * NHEADS + h] = pl;
            ar[node * NHEADS + h] = pr;
        }
    }
}

// ---------------- edge softmax weights (normalized), wave per node ----------------

__global__ __launch_bounds__(256) void weight_kernel(const float* __restrict__ al,
                                                     const float* __restrict__ ar,
                                                     const int* __restrict__ rowp,
                                                     const int* __restrict__ esrc,
                                                     float* __restrict__ wgt, int n) {
    int node = blockIdx.x * 4 + (threadIdx.x >> 6);
    int lane = threadIdx.x & 63;
    if (node >= n) return;
    int e0 = rowp[node], e1 = rowp[node + 1];
    float ar0 = ar[node * 3 + 0], ar1 = ar[node * 3 + 1], ar2 = ar[node * 3 + 2];
    // pass 1: max
    float m0 = -1e30f, m1 = -1e30f, m2 = -1e30f;
    for (int p = e0 + lane; p < e1; p += 64) {
        int s = esrc[p];
        m0 = fmaxf(m0, lrelu(al[s * 3 + 0] + ar0));
        m1 = fmaxf(m1, lrelu(al[s * 3 + 1] + ar1));
        m2 = fmaxf(m2, lrelu(al[s * 3 + 2] + ar2));
    }
#pragma unroll
    for (int off = 32; off; off >>= 1) {
        m0 = fmaxf(m0, __shfl_xor(m0, off));
        m1 = fmaxf(m1, __shfl_xor(m1, off));
        m2 = fmaxf(m2, __shfl_xor(m2, off));
    }
    // pass 2: denom
    float s0 = 0.f, s1 = 0.f, s2 = 0.f;
    for (int p = e0 + lane; p < e1; p += 64) {
        int s = esrc[p];
        s0 += __expf(lrelu(al[s * 3 + 0] + ar0) - m0);
        s1 += __expf(lrelu(al[s * 3 + 1] + ar1) - m1);
        s2 += __expf(lrelu(al[s * 3 + 2] + ar2) - m2);
    }
#pragma unroll
    for (int off = 32; off; off >>= 1) {
        s0 += __shfl_xor(s0, off);
        s1 += __shfl_xor(s1, off);
        s2 += __shfl_xor(s2, off);
    }
    float r0 = 1.f / (s0 + 1e-16f), r1 = 1.f / (s1 + 1e-16f), r2 = 1.f / (s2 + 1e-16f);
    // pass 3: write normalized weights
    for (int p = e0 + lane; p < e1; p += 64) {
        int s = esrc[p];
        wgt[p * 3 + 0] = __expf(lrelu(al[s * 3 + 0] + ar0) - m0) * r0;
        wgt[p * 3 + 1] = __expf(lrelu(al[s * 3 + 1] + ar1) - m1) * r1;
        wgt[p * 3 + 2] = __expf(lrelu(al[s * 3 + 2] + ar2) - m2) * r2;
    }
}

// ---------------- gather: block per node, wave per head ----------------

template <bool RELU>
__global__ __launch_bounds__(192) void gather_kernel(const float* __restrict__ hfeat,
                                                     const float* __restrict__ wgt,
                                                     const int* __restrict__ rowp,
                                                     const int* __restrict__ esrc,
                                                     const float* __restrict__ bias,
                                                     float* __restrict__ out, int n) {
    int node = blockIdx.x;
    int head = threadIdx.x >> 6;
    int lane = threadIdx.x & 63;
    int e0 = rowp[node], e1 = rowp[node + 1];
    const float* base = hfeat + head * HIDC + lane;
    float acc = 0.f;
    int e = e0;
    // 4-deep batched for ILP (independent gather loads in flight)
    for (; e + 4 <= e1; e += 4) {
        int s0 = esrc[e + 0], s1 = esrc[e + 1], s2 = esrc[e + 2], s3 = esrc[e + 3];
        float w0 = wgt[(e + 0) * 3 + head];
        float w1 = wgt[(e + 1) * 3 + head];
        float w2 = wgt[(e + 2) * 3 + head];
        float w3 = wgt[(e + 3) * 3 + head];
        float h0 = base[(size_t)s0 * HC];
        float h1 = base[(size_t)s1 * HC];
        float h2 = base[(size_t)s2 * HC];
        float h3 = base[(size_t)s3 * HC];
        acc += w0 * h0 + w1 * h1 + w2 * h2 + w3 * h3;
    }
    for (; e < e1; ++e) {
        int s = esrc[e];
        acc += wgt[e * 3 + head] * base[(size_t)s * HC];
    }
    float v = acc + bias[head * HIDC + lane];
    if (RELU) v = fmaxf(v, 0.f);
    out[(size_t)node * HC + head * HIDC + lane] = v;
}

// ---------------- launch ----------------

extern "C" void kernel_launch(void* const* d_in, const int* in_sizes, int n_in,
                              void* d_out, int out_size, void* d_ws, size_t ws_size,
                              hipStream_t stream) {
    const float* x     = (const float*)d_in[0];
    const int*   ei    = (const int*)d_in[1];   // [2,E] int
    const float* W1    = (const float*)d_in[2];
    const float* attl1 = (const float*)d_in[3];
    const float* attr1 = (const float*)d_in[4];
    const float* b1    = (const float*)d_in[5];
    const float* W2    = (const float*)d_in[6];
    const float* attl2 = (const float*)d_in[7];
    const float* attr2 = (const float*)d_in[8];
    const float* b2    = (const float*)d_in[9];
    const float* Wo    = (const float*)d_in[10];
    const float* bo    = (const float*)d_in[11];
    float* outp = (float*)d_out;

    const int n = NNODES;
    const int E_ = NEDGES;
    const int ET = E_ + n;

    char* ws = (char*)d_ws;
    size_t off = 0;
    auto take = [&](size_t bytes) {
        size_t p = off;
        off += (bytes + 255) & ~(size_t)255;
        return p;
    };
    float* A    = (float*)(ws + take((size_t)n * HC * 4));
    float* B    = (float*)(ws + take((size_t)n * HC * 4));
    float* al   = (float*)(ws + take((size_t)n * 3 * 4));
    float* ar   = (float*)(ws + take((size_t)n * 3 * 4));
    int* rowp   = (int*)(ws + take((size_t)(n + 1) * 4));
    int* deg    = (int*)(ws + take((size_t)n * 4));
    int* cursor = (int*)(ws + take((size_t)n * 4));
    int* esrc   = (int*)(ws + take((size_t)ET * 4));
    (void)ws_size;
    // normalized edge weights live in d_out (5.4 MB < 8 MB); head GEMM
    // overwrites every element of d_out afterwards, so final contents are clean.
    float* wgt = (float*)d_out;

    hipMemsetAsync(deg, 0, (size_t)n * 4, stream);
    hipMemsetAsync(cursor, 0, (size_t)n * 4, stream);

    int eb = 256;
    int eg = (ET + eb - 1) / eb;
    hist_kernel<<<eg, eb, 0, stream>>>(ei, deg, E_, n);
    scan_kernel<<<1, 1024, 0, stream>>>(deg, rowp, n);
    scatter_kernel<<<eg, eb, 0, stream>>>(ei, rowp, cursor, esrc, E_, n);

    dim3 g1((n + 255) / 256, HC / 64);
    dim3 go((n + 255) / 256, 1);
    int nodeg4 = (n + 3) / 4;

    // layer 1
    gemm_xwt<128, HC, false><<<g1, 256, 0, stream>>>(x, W1, nullptr, A, n);
    attproj_kernel<<<nodeg4, 256, 0, stream>>>(A, attl1, attr1, al, ar, n);
    weight_kernel<<<nodeg4, 256, 0, stream>>>(al, ar, rowp, esrc, wgt, n);
    gather_kernel<true><<<n, 192, 0, stream>>>(A, wgt, rowp, esrc, b1, B, n);
    // layer 2
    gemm_xwt<HC, HC, false><<<g1, 256, 0, stream>>>(B, W2, nullptr, A, n);
    attproj_kernel<<<nodeg4, 256, 0, stream>>>(A, attl2, attr2, al, ar, n);
    weight_kernel<<<nodeg4, 256, 0, stream>>>(al, ar, rowp, esrc, wgt, n);
    gather_kernel<true><<<n, 192, 0, stream>>>(A, wgt, rowp, esrc, b2, B, n);
    // output head
    gemm_xwt<HC, NCLS, true><<<go, 256, 0, stream>>>(B, Wo, bo, outp, n);
}

// Round 4
// 462.166 us; speedup vs baseline: 2.0183x; 1.1005x over previous
//
#include <hip/hip_runtime.h>
#include <hip/hip_bf16.h>

// GAT 2-layer + linear head. All fp32.
// N=50000, E=400000 (+N self loops), IN_DIM=128, HEADS=3, HID=64 (HC=192), CLASSES=40.

#define NNODES 50000
#define NEDGES 400000
#define HC 192
#define NHEADS 3
#define HIDC 64
#define NCLS 40

__device__ __forceinline__ float lrelu(float a) { return a > 0.f ? a : 0.2f * a; }

// ---------------- CSR build ----------------

__global__ void hist_kernel(const int* __restrict__ ei, int* __restrict__ deg,
                            int E_, int n) {
    int e = blockIdx.x * blockDim.x + threadIdx.x;
    int ET = E_ + n;
    if (e >= ET) return;
    int d = (e < E_) ? ei[E_ + e] : (e - E_);
    atomicAdd(&deg[d], 1);
}

__global__ __launch_bounds__(1024) void scan_kernel(const int* __restrict__ deg,
                                                    int* __restrict__ rowp, int n) {
    __shared__ int sums[1024];
    int tid = threadIdx.x;
    int per = (n + 1023) >> 10;
    int begin = tid * per;
    int end = begin + per; if (end > n) end = n;
    int s = 0;
    for (int i = begin; i < end && i < n; ++i) s += deg[i];
    sums[tid] = s;
    __syncthreads();
    for (int off = 1; off < 1024; off <<= 1) {
        int v = (tid >= off) ? sums[tid - off] : 0;
        __syncthreads();
        sums[tid] += v;
        __syncthreads();
    }
    int run = (tid == 0) ? 0 : sums[tid - 1];
    for (int i = begin; i < end && i < n; ++i) {
        rowp[i] = run;
        run += deg[i];
    }
    if (tid == 1023) rowp[n] = sums[1023];
}

__global__ void scatter_kernel(const int* __restrict__ ei, const int* __restrict__ rowp,
                               int* __restrict__ cursor, int* __restrict__ esrc,
                               int E_, int n) {
    int e = blockIdx.x * blockDim.x + threadIdx.x;
    int ET = E_ + n;
    if (e >= ET) return;
    int s, d;
    if (e < E_) { s = ei[e]; d = ei[E_ + e]; }
    else        { s = e - E_; d = s; }
    int pos = atomicAdd(&cursor[d], 1);
    esrc[rowp[d] + pos] = s;
}

// ---------------- GEMM: C[n,M] = X[n,K] @ W[M,K]^T (+bias) ----------------
// BM=128, BN=64, BK=16, 256 threads, per-thread 8x4.
// Grid 391x3 = 1173 blocks (~4.6/CU) -> occupancy-limited no more (R3: 256-tile
// gave only 2.3 blocks/CU, Occ 13.7%, VALUBusy 29%). ~70 VGPR, no spill risk.

template <int K, int M, bool ADD_BIAS>
__global__ __launch_bounds__(256) void gemm_xwt(const float* __restrict__ X,
                                                const float* __restrict__ W,
                                                const float* __restrict__ bias,
                                                float* __restrict__ C, int n) {
    const int BM = 128, BN = 64, BK = 16;
    __shared__ float Xs[BK][BM + 4];
    __shared__ float Ws[BK][BN + 4];
    int bm = blockIdx.x * BM;
    int bn = blockIdx.y * BN;
    int tid = threadIdx.x;
    int tx = tid & 15;   // 16 col groups of 4
    int ty = tid >> 4;   // 16 row groups of 8
    float acc[8][4] = {};

    for (int k0 = 0; k0 < K; k0 += BK) {
        // X tile: 128x16 floats = 512 float4, 2 per thread
#pragma unroll
        for (int t = 0; t < 2; ++t) {
            int q = tid + t * 256;
            int row = q >> 2;
            int ks = (q & 3) * 4;
            int grow = bm + row;
            float4 v = make_float4(0.f, 0.f, 0.f, 0.f);
            if (grow < n) v = *(const float4*)(X + (size_t)grow * K + k0 + ks);
            Xs[ks + 0][row] = v.x; Xs[ks + 1][row] = v.y;
            Xs[ks + 2][row] = v.z; Xs[ks + 3][row] = v.w;
        }
        // W tile: 64x16 floats = 256 float4, 1 per thread
        {
            int rowm = tid >> 2;
            int ks = (tid & 3) * 4;
            int gm = bn + rowm;
            float4 v = make_float4(0.f, 0.f, 0.f, 0.f);
            if (gm < M) v = *(const float4*)(W + (size_t)gm * K + k0 + ks);
            Ws[ks + 0][rowm] = v.x; Ws[ks + 1][rowm] = v.y;
            Ws[ks + 2][rowm] = v.z; Ws[ks + 3][rowm] = v.w;
        }
        __syncthreads();
#pragma unroll
        for (int kk = 0; kk < BK; ++kk) {
            float4 xa = *(const float4*)&Xs[kk][ty * 8];
            float4 xb = *(const float4*)&Xs[kk][ty * 8 + 4];
            float4 wa = *(const float4*)&Ws[kk][tx * 4];
            float xr[8] = {xa.x, xa.y, xa.z, xa.w, xb.x, xb.y, xb.z, xb.w};
            float wr[4] = {wa.x, wa.y, wa.z, wa.w};
#pragma unroll
            for (int i = 0; i < 8; ++i)
#pragma unroll
                for (int j = 0; j < 4; ++j) acc[i][j] += xr[i] * wr[j];
        }
        __syncthreads();
    }
#pragma unroll
    for (int i = 0; i < 8; ++i) {
        int grow = bm + ty * 8 + i;
        if (grow >= n) continue;
        int gcol = bn + tx * 4;
        if (gcol + 3 < M) {
            float4 v;
            v.x = acc[i][0]; v.y = acc[i][1]; v.z = acc[i][2]; v.w = acc[i][3];
            if (ADD_BIAS) {
                v.x += bias[gcol + 0]; v.y += bias[gcol + 1];
                v.z += bias[gcol + 2]; v.w += bias[gcol + 3];
            }
            *(float4*)(C + (size_t)grow * M + gcol) = v;
        } else {
#pragma unroll
            for (int j = 0; j < 4; ++j) {
                int gc = gcol + j;
                if (gc < M) {
                    float v = acc[i][j];
                    if (ADD_BIAS) v += bias[gc];
                    C[(size_t)grow * M + gc] = v;
                }
            }
        }
    }
}

// ---------------- attention projections: al/ar [n,3] ----------------

__global__ __launch_bounds__(256) void attproj_kernel(const float* __restrict__ A,
                                                      const float* __restrict__ attl,
                                                      const float* __restrict__ attr,
                                                      float* __restrict__ al,
                                                      float* __restrict__ ar, int n) {
    int wave = threadIdx.x >> 6;
    int lane = threadIdx.x & 63;
    int node = blockIdx.x * 4 + wave;
    if (node >= n) return;
#pragma unroll
    for (int h = 0; h < NHEADS; ++h) {
        float v = A[(size_t)node * HC + h * HIDC + lane];
        float pl = v * attl[h * HIDC + lane];
        float pr = v * attr[h * HIDC + lane];
#pragma unroll
        for (int off = 32; off; off >>= 1) {
            pl += __shfl_xor(pl, off);
            pr += __shfl_xor(pr, off);
        }
        if (lane == 0) {
            al[node * NHEADS + h] = pl;
            ar[node * NHEADS + h] = pr;
        }
    }
}

// ---------------- edge softmax weights (normalized), wave per node ----------------

__global__ __launch_bounds__(256) void weight_kernel(const float* __restrict__ al,
                                                     const float* __restrict__ ar,
                                                     const int* __restrict__ rowp,
                                                     const int* __restrict__ esrc,
                                                     float* __restrict__ wgt, int n) {
    int node = blockIdx.x * 4 + (threadIdx.x >> 6);
    int lane = threadIdx.x & 63;
    if (node >= n) return;
    int e0 = rowp[node], e1 = rowp[node + 1];
    float ar0 = ar[node * 3 + 0], ar1 = ar[node * 3 + 1], ar2 = ar[node * 3 + 2];
    float m0 = -1e30f, m1 = -1e30f, m2 = -1e30f;
    for (int p = e0 + lane; p < e1; p += 64) {
        int s = esrc[p];
        m0 = fmaxf(m0, lrelu(al[s * 3 + 0] + ar0));
        m1 = fmaxf(m1, lrelu(al[s * 3 + 1] + ar1));
        m2 = fmaxf(m2, lrelu(al[s * 3 + 2] + ar2));
    }
#pragma unroll
    for (int off = 32; off; off >>= 1) {
        m0 = fmaxf(m0, __shfl_xor(m0, off));
        m1 = fmaxf(m1, __shfl_xor(m1, off));
        m2 = fmaxf(m2, __shfl_xor(m2, off));
    }
    float s0 = 0.f, s1 = 0.f, s2 = 0.f;
    for (int p = e0 + lane; p < e1; p += 64) {
        int s = esrc[p];
        s0 += __expf(lrelu(al[s * 3 + 0] + ar0) - m0);
        s1 += __expf(lrelu(al[s * 3 + 1] + ar1) - m1);
        s2 += __expf(lrelu(al[s * 3 + 2] + ar2) - m2);
    }
#pragma unroll
    for (int off = 32; off; off >>= 1) {
        s0 += __shfl_xor(s0, off);
        s1 += __shfl_xor(s1, off);
        s2 += __shfl_xor(s2, off);
    }
    float r0 = 1.f / (s0 + 1e-16f), r1 = 1.f / (s1 + 1e-16f), r2 = 1.f / (s2 + 1e-16f);
    for (int p = e0 + lane; p < e1; p += 64) {
        int s = esrc[p];
        wgt[p * 3 + 0] = __expf(lrelu(al[s * 3 + 0] + ar0) - m0) * r0;
        wgt[p * 3 + 1] = __expf(lrelu(al[s * 3 + 1] + ar1) - m1) * r1;
        wgt[p * 3 + 2] = __expf(lrelu(al[s * 3 + 2] + ar2) - m2) * r2;
    }
}

// ---------------- gather: wave per (node, head); 4 edge-groups x 16 lanes ----------------
// Each 16-lane group streams a different edge's 256B head-row as float4
// (16B/lane) -> 4 edge-rows in flight per wave, 2x unrolled = 8.
// Cross-group reduce via shfl_xor(16/32); lanes 0-15 write the row.

template <bool RELU>
__global__ __launch_bounds__(256) void gather_kernel(const float* __restrict__ hfeat,
                                                     const float* __restrict__ wgt,
                                                     const int* __restrict__ rowp,
                                                     const int* __restrict__ esrc,
                                                     const float* __restrict__ bias,
                                                     float* __restrict__ out, int nunits) {
    int unit = blockIdx.x * 4 + (threadIdx.x >> 6);
    if (unit >= nunits) return;
    int node = unit / 3;
    int head = unit - node * 3;
    int lane = threadIdx.x & 63;
    int g = lane >> 4;        // edge group 0..3
    int c4 = lane & 15;       // float4 slot within the 64-float head row
    int e0 = rowp[node], e1 = rowp[node + 1];
    const float* base = hfeat + (size_t)head * HIDC + c4 * 4;

    float4 acc = make_float4(0.f, 0.f, 0.f, 0.f);
    int e = e0 + g;
    for (; e + 4 < e1; e += 8) {
        int s0 = esrc[e];
        int s1 = esrc[e + 4];
        float w0 = wgt[e * 3 + head];
        float w1 = wgt[(e + 4) * 3 + head];
        float4 h0 = *(const float4*)(base + (size_t)s0 * HC);
        float4 h1 = *(const float4*)(base + (size_t)s1 * HC);
        acc.x += w0 * h0.x + w1 * h1.x;
        acc.y += w0 * h0.y + w1 * h1.y;
        acc.z += w0 * h0.z + w1 * h1.z;
        acc.w += w0 * h0.w + w1 * h1.w;
    }
    if (e < e1) {
        int s0 = esrc[e];
        float w0 = wgt[e * 3 + head];
        float4 h0 = *(const float4*)(base + (size_t)s0 * HC);
        acc.x += w0 * h0.x; acc.y += w0 * h0.y;
        acc.z += w0 * h0.z; acc.w += w0 * h0.w;
    }
#pragma unroll
    for (int off = 16; off <= 32; off <<= 1) {
        acc.x += __shfl_xor(acc.x, off);
        acc.y += __shfl_xor(acc.y, off);
        acc.z += __shfl_xor(acc.z, off);
        acc.w += __shfl_xor(acc.w, off);
    }
    if (g == 0) {
        const float4 bv = *(const float4*)(bias + head * HIDC + c4 * 4);
        float4 v;
        v.x = acc.x + bv.x; v.y = acc.y + bv.y;
        v.z = acc.z + bv.z; v.w = acc.w + bv.w;
        if (RELU) {
            v.x = fmaxf(v.x, 0.f); v.y = fmaxf(v.y, 0.f);
            v.z = fmaxf(v.z, 0.f); v.w = fmaxf(v.w, 0.f);
        }
        *(float4*)(out + (size_t)node * HC + head * HIDC + c4 * 4) = v;
    }
}

// ---------------- launch ----------------

extern "C" void kernel_launch(void* const* d_in, const int* in_sizes, int n_in,
                              void* d_out, int out_size, void* d_ws, size_t ws_size,
                              hipStream_t stream) {
    const float* x     = (const float*)d_in[0];
    const int*   ei    = (const int*)d_in[1];   // [2,E] int
    const float* W1    = (const float*)d_in[2];
    const float* attl1 = (const float*)d_in[3];
    const float* attr1 = (const float*)d_in[4];
    const float* b1    = (const float*)d_in[5];
    const float* W2    = (const float*)d_in[6];
    const float* attl2 = (const float*)d_in[7];
    const float* attr2 = (const float*)d_in[8];
    const float* b2    = (const float*)d_in[9];
    const float* Wo    = (const float*)d_in[10];
    const float* bo    = (const float*)d_in[11];
    float* outp = (float*)d_out;

    const int n = NNODES;
    const int E_ = NEDGES;
    const int ET = E_ + n;

    char* ws = (char*)d_ws;
    size_t off = 0;
    auto take = [&](size_t bytes) {
        size_t p = off;
        off += (bytes + 255) & ~(size_t)255;
        return p;
    };
    float* A    = (float*)(ws + take((size_t)n * HC * 4));
    float* B    = (float*)(ws + take((size_t)n * HC * 4));
    float* al   = (float*)(ws + take((size_t)n * 3 * 4));
    float* ar   = (float*)(ws + take((size_t)n * 3 * 4));
    int* rowp   = (int*)(ws + take((size_t)(n + 1) * 4));
    int* deg    = (int*)(ws + take((size_t)n * 4));
    int* cursor = (int*)(ws + take((size_t)n * 4));
    int* esrc   = (int*)(ws + take((size_t)ET * 4));
    (void)ws_size;
    // normalized edge weights live in d_out (5.4 MB < 8 MB); head GEMM
    // overwrites every element of d_out afterwards, so final contents are clean.
    float* wgt = (float*)d_out;

    hipMemsetAsync(deg, 0, (size_t)n * 4, stream);
    hipMemsetAsync(cursor, 0, (size_t)n * 4, stream);

    int eb = 256;
    int eg = (ET + eb - 1) / eb;
    hist_kernel<<<eg, eb, 0, stream>>>(ei, deg, E_, n);
    scan_kernel<<<1, 1024, 0, stream>>>(deg, rowp, n);
    scatter_kernel<<<eg, eb, 0, stream>>>(ei, rowp, cursor, esrc, E_, n);

    dim3 g1((n + 127) / 128, HC / 64);
    dim3 go((n + 127) / 128, 1);
    int nodeg4 = (n + 3) / 4;
    int nunits = n * NHEADS;
    int gatherg = (nunits + 3) / 4;

    // layer 1
    gemm_xwt<128, HC, false><<<g1, 256, 0, stream>>>(x, W1, nullptr, A, n);
    attproj_kernel<<<nodeg4, 256, 0, stream>>>(A, attl1, attr1, al, ar, n);
    weight_kernel<<<nodeg4, 256, 0, stream>>>(al, ar, rowp, esrc, wgt, n);
    gather_kernel<true><<<gatherg, 256, 0, stream>>>(A, wgt, rowp, esrc, b1, B, nunits);
    // layer 2
    gemm_xwt<HC, HC, false><<<g1, 256, 0, stream>>>(B, W2, nullptr, A, n);
    attproj_kernel<<<nodeg4, 256, 0, stream>>>(A, attl2, attr2, al, ar, n);
    weight_kernel<<<nodeg4, 256, 0, stream>>>(al, ar, rowp, esrc, wgt, n);
    gather_kernel<true><<<gatherg, 256, 0, stream>>>(A, wgt, rowp, esrc, b2, B, nunits);
    // output head
    gemm_xwt<HC, NCLS, true><<<go, 256, 0, stream>>>(B, Wo, bo, outp, n);
}

// Round 5
// 391.570 us; speedup vs baseline: 2.3821x; 1.1803x over previous
//
#include <hip/hip_runtime.h>
#include <hip/hip_bf16.h>

// GAT 2-layer + linear head. All fp32.
// N=50000, E=400000 (+N self loops), IN_DIM=128, HEADS=3, HID=64 (HC=192), CLASSES=40.

#define NNODES 50000
#define NEDGES 400000
#define HC 192
#define NHEADS 3
#define HIDC 64
#define NCLS 40

// hierarchical scan geometry: 256 chunks of 196 elements cover 50176 >= N
#define SB 256
#define CHUNK 196

__device__ __forceinline__ float lrelu(float a) { return a > 0.f ? a : 0.2f * a; }

// ---------------- CSR build ----------------

__global__ void hist_kernel(const int* __restrict__ ei, int* __restrict__ deg,
                            int E_, int n) {
    int e = blockIdx.x * blockDim.x + threadIdx.x;
    int ET = E_ + n;
    if (e >= ET) return;
    int d = (e < E_) ? ei[E_ + e] : (e - E_);
    atomicAdd(&deg[d], 1);
}

// R4: single-block scan was 77us (one CU, latency-bound). 3-level scan instead.

__global__ __launch_bounds__(256) void bsum_kernel(const int* __restrict__ deg,
                                                   int* __restrict__ bsum, int n) {
    int b = blockIdx.x, t = threadIdx.x;
    int i = b * CHUNK + t;
    int v = (t < CHUNK && i < n) ? deg[i] : 0;
#pragma unroll
    for (int off = 32; off; off >>= 1) v += __shfl_xor(v, off);
    __shared__ int sh[4];
    if ((t & 63) == 0) sh[t >> 6] = v;
    __syncthreads();
    if (t == 0) bsum[b] = sh[0] + sh[1] + sh[2] + sh[3];
}

__global__ __launch_bounds__(256) void bscan_kernel(const int* __restrict__ bsum,
                                                    int* __restrict__ boff,
                                                    int* __restrict__ rowp, int n) {
    __shared__ int sh[SB];
    int t = threadIdx.x;
    int v = bsum[t];
    sh[t] = v;
    __syncthreads();
    for (int off = 1; off < SB; off <<= 1) {
        int u = (t >= off) ? sh[t - off] : 0;
        __syncthreads();
        sh[t] += u;
        __syncthreads();
    }
    boff[t] = sh[t] - v;               // exclusive
    if (t == SB - 1) rowp[n] = sh[t];  // total
}

__global__ __launch_bounds__(256) void scan_chunk_kernel(const int* __restrict__ deg,
                                                         const int* __restrict__ boff,
                                                         int* __restrict__ rowp, int n) {
    __shared__ int sh[256];
    int b = blockIdx.x, t = threadIdx.x;
    int i = b * CHUNK + t;
    int v = (t < CHUNK && i < n) ? deg[i] : 0;
    sh[t] = v;
    __syncthreads();
    for (int off = 1; off < 256; off <<= 1) {
        int u = (t >= off) ? sh[t - off] : 0;
        __syncthreads();
        sh[t] += u;
        __syncthreads();
    }
    if (t < CHUNK && i < n) rowp[i] = boff[b] + sh[t] - v;
}

__global__ void scatter_kernel(const int* __restrict__ ei, const int* __restrict__ rowp,
                               int* __restrict__ cursor, int* __restrict__ esrc,
                               int E_, int n) {
    int e = blockIdx.x * blockDim.x + threadIdx.x;
    int ET = E_ + n;
    if (e >= ET) return;
    int s, d;
    if (e < E_) { s = ei[e]; d = ei[E_ + e]; }
    else        { s = e - E_; d = s; }
    int pos = atomicAdd(&cursor[d], 1);
    esrc[rowp[d] + pos] = s;
}

// ---------------- GEMM: C[n,M] = X[n,K] @ W[M,K]^T (+bias) ----------------
// BM=128, BN=64, BK=16, 256 threads, per-thread 8x4. ~70 VGPR, 1173 blocks.

template <int K, int M, bool ADD_BIAS>
__global__ __launch_bounds__(256) void gemm_xwt(const float* __restrict__ X,
                                                const float* __restrict__ W,
                                                const float* __restrict__ bias,
                                                float* __restrict__ C, int n) {
    const int BM = 128, BN = 64, BK = 16;
    __shared__ float Xs[BK][BM + 4];
    __shared__ float Ws[BK][BN + 4];
    int bm = blockIdx.x * BM;
    int bn = blockIdx.y * BN;
    int tid = threadIdx.x;
    int tx = tid & 15;   // 16 col groups of 4
    int ty = tid >> 4;   // 16 row groups of 8
    float acc[8][4] = {};

    for (int k0 = 0; k0 < K; k0 += BK) {
#pragma unroll
        for (int t = 0; t < 2; ++t) {
            int q = tid + t * 256;
            int row = q >> 2;
            int ks = (q & 3) * 4;
            int grow = bm + row;
            float4 v = make_float4(0.f, 0.f, 0.f, 0.f);
            if (grow < n) v = *(const float4*)(X + (size_t)grow * K + k0 + ks);
            Xs[ks + 0][row] = v.x; Xs[ks + 1][row] = v.y;
            Xs[ks + 2][row] = v.z; Xs[ks + 3][row] = v.w;
        }
        {
            int rowm = tid >> 2;
            int ks = (tid & 3) * 4;
            int gm = bn + rowm;
            float4 v = make_float4(0.f, 0.f, 0.f, 0.f);
            if (gm < M) v = *(const float4*)(W + (size_t)gm * K + k0 + ks);
            Ws[ks + 0][rowm] = v.x; Ws[ks + 1][rowm] = v.y;
            Ws[ks + 2][rowm] = v.z; Ws[ks + 3][rowm] = v.w;
        }
        __syncthreads();
#pragma unroll
        for (int kk = 0; kk < BK; ++kk) {
            float4 xa = *(const float4*)&Xs[kk][ty * 8];
            float4 xb = *(const float4*)&Xs[kk][ty * 8 + 4];
            float4 wa = *(const float4*)&Ws[kk][tx * 4];
            float xr[8] = {xa.x, xa.y, xa.z, xa.w, xb.x, xb.y, xb.z, xb.w};
            float wr[4] = {wa.x, wa.y, wa.z, wa.w};
#pragma unroll
            for (int i = 0; i < 8; ++i)
#pragma unroll
                for (int j = 0; j < 4; ++j) acc[i][j] += xr[i] * wr[j];
        }
        __syncthreads();
    }
#pragma unroll
    for (int i = 0; i < 8; ++i) {
        int grow = bm + ty * 8 + i;
        if (grow >= n) continue;
        int gcol = bn + tx * 4;
        if (gcol + 3 < M) {
            float4 v;
            v.x = acc[i][0]; v.y = acc[i][1]; v.z = acc[i][2]; v.w = acc[i][3];
            if (ADD_BIAS) {
                v.x += bias[gcol + 0]; v.y += bias[gcol + 1];
                v.z += bias[gcol + 2]; v.w += bias[gcol + 3];
            }
            *(float4*)(C + (size_t)grow * M + gcol) = v;
        } else {
#pragma unroll
            for (int j = 0; j < 4; ++j) {
                int gc = gcol + j;
                if (gc < M) {
                    float v = acc[i][j];
                    if (ADD_BIAS) v += bias[gc];
                    C[(size_t)grow * M + gc] = v;
                }
            }
        }
    }
}

// ---------------- attention projections: al/ar [n,3] ----------------

__global__ __launch_bounds__(256) void attproj_kernel(const float* __restrict__ A,
                                                      const float* __restrict__ attl,
                                                      const float* __restrict__ attr,
                                                      float* __restrict__ al,
                                                      float* __restrict__ ar, int n) {
    int wave = threadIdx.x >> 6;
    int lane = threadIdx.x & 63;
    int node = blockIdx.x * 4 + wave;
    if (node >= n) return;
#pragma unroll
    for (int h = 0; h < NHEADS; ++h) {
        float v = A[(size_t)node * HC + h * HIDC + lane];
        float pl = v * attl[h * HIDC + lane];
        float pr = v * attr[h * HIDC + lane];
#pragma unroll
        for (int off = 32; off; off >>= 1) {
            pl += __shfl_xor(pl, off);
            pr += __shfl_xor(pr, off);
        }
        if (lane == 0) {
            al[node * NHEADS + h] = pl;
            ar[node * NHEADS + h] = pr;
        }
    }
}

// ---------------- edge softmax weights (normalized), wave per node ----------------

__global__ __launch_bounds__(256) void weight_kernel(const float* __restrict__ al,
                                                     const float* __restrict__ ar,
                                                     const int* __restrict__ rowp,
                                                     const int* __restrict__ esrc,
                                                     float* __restrict__ wgt, int n) {
    int node = blockIdx.x * 4 + (threadIdx.x >> 6);
    int lane = threadIdx.x & 63;
    if (node >= n) return;
    int e0 = rowp[node], e1 = rowp[node + 1];
    float ar0 = ar[node * 3 + 0], ar1 = ar[node * 3 + 1], ar2 = ar[node * 3 + 2];
    float m0 = -1e30f, m1 = -1e30f, m2 = -1e30f;
    for (int p = e0 + lane; p < e1; p += 64) {
        int s = esrc[p];
        m0 = fmaxf(m0, lrelu(al[s * 3 + 0] + ar0));
        m1 = fmaxf(m1, lrelu(al[s * 3 + 1] + ar1));
        m2 = fmaxf(m2, lrelu(al[s * 3 + 2] + ar2));
    }
#pragma unroll
    for (int off = 32; off; off >>= 1) {
        m0 = fmaxf(m0, __shfl_xor(m0, off));
        m1 = fmaxf(m1, __shfl_xor(m1, off));
        m2 = fmaxf(m2, __shfl_xor(m2, off));
    }
    float s0 = 0.f, s1 = 0.f, s2 = 0.f;
    for (int p = e0 + lane; p < e1; p += 64) {
        int s = esrc[p];
        s0 += __expf(lrelu(al[s * 3 + 0] + ar0) - m0);
        s1 += __expf(lrelu(al[s * 3 + 1] + ar1) - m1);
        s2 += __expf(lrelu(al[s * 3 + 2] + ar2) - m2);
    }
#pragma unroll
    for (int off = 32; off; off >>= 1) {
        s0 += __shfl_xor(s0, off);
        s1 += __shfl_xor(s1, off);
        s2 += __shfl_xor(s2, off);
    }
    float r0 = 1.f / (s0 + 1e-16f), r1 = 1.f / (s1 + 1e-16f), r2 = 1.f / (s2 + 1e-16f);
    for (int p = e0 + lane; p < e1; p += 64) {
        int s = esrc[p];
        wgt[p * 3 + 0] = __expf(lrelu(al[s * 3 + 0] + ar0) - m0) * r0;
        wgt[p * 3 + 1] = __expf(lrelu(al[s * 3 + 1] + ar1) - m1) * r1;
        wgt[p * 3 + 2] = __expf(lrelu(al[s * 3 + 2] + ar2) - m2) * r2;
    }
}

// ---------------- gather: wave per (node, head); 4 edge-groups x 16 lanes ----------------

template <bool RELU>
__global__ __launch_bounds__(256) void gather_kernel(const float* __restrict__ hfeat,
                                                     const float* __restrict__ wgt,
                                                     const int* __restrict__ rowp,
                                                     const int* __restrict__ esrc,
                                                     const float* __restrict__ bias,
                                                     float* __restrict__ out, int nunits) {
    int unit = blockIdx.x * 4 + (threadIdx.x >> 6);
    if (unit >= nunits) return;
    int node = unit / 3;
    int head = unit - node * 3;
    int lane = threadIdx.x & 63;
    int g = lane >> 4;        // edge group 0..3
    int c4 = lane & 15;       // float4 slot within the 64-float head row
    int e0 = rowp[node], e1 = rowp[node + 1];
    const float* base = hfeat + (size_t)head * HIDC + c4 * 4;

    float4 acc = make_float4(0.f, 0.f, 0.f, 0.f);
    int e = e0 + g;
    for (; e + 4 < e1; e += 8) {
        int s0 = esrc[e];
        int s1 = esrc[e + 4];
        float w0 = wgt[e * 3 + head];
        float w1 = wgt[(e + 4) * 3 + head];
        float4 h0 = *(const float4*)(base + (size_t)s0 * HC);
        float4 h1 = *(const float4*)(base + (size_t)s1 * HC);
        acc.x += w0 * h0.x + w1 * h1.x;
        acc.y += w0 * h0.y + w1 * h1.y;
        acc.z += w0 * h0.z + w1 * h1.z;
        acc.w += w0 * h0.w + w1 * h1.w;
    }
    if (e < e1) {
        int s0 = esrc[e];
        float w0 = wgt[e * 3 + head];
        float4 h0 = *(const float4*)(base + (size_t)s0 * HC);
        acc.x += w0 * h0.x; acc.y += w0 * h0.y;
        acc.z += w0 * h0.z; acc.w += w0 * h0.w;
    }
#pragma unroll
    for (int off = 16; off <= 32; off <<= 1) {
        acc.x += __shfl_xor(acc.x, off);
        acc.y += __shfl_xor(acc.y, off);
        acc.z += __shfl_xor(acc.z, off);
        acc.w += __shfl_xor(acc.w, off);
    }
    if (g == 0) {
        const float4 bv = *(const float4*)(bias + head * HIDC + c4 * 4);
        float4 v;
        v.x = acc.x + bv.x; v.y = acc.y + bv.y;
        v.z = acc.z + bv.z; v.w = acc.w + bv.w;
        if (RELU) {
            v.x = fmaxf(v.x, 0.f); v.y = fmaxf(v.y, 0.f);
            v.z = fmaxf(v.z, 0.f); v.w = fmaxf(v.w, 0.f);
        }
        *(float4*)(out + (size_t)node * HC + head * HIDC + c4 * 4) = v;
    }
}

// ---------------- launch ----------------

extern "C" void kernel_launch(void* const* d_in, const int* in_sizes, int n_in,
                              void* d_out, int out_size, void* d_ws, size_t ws_size,
                              hipStream_t stream) {
    const float* x     = (const float*)d_in[0];
    const int*   ei    = (const int*)d_in[1];   // [2,E] int
    const float* W1    = (const float*)d_in[2];
    const float* attl1 = (const float*)d_in[3];
    const float* attr1 = (const float*)d_in[4];
    const float* b1    = (const float*)d_in[5];
    const float* W2    = (const float*)d_in[6];
    const float* attl2 = (const float*)d_in[7];
    const float* attr2 = (const float*)d_in[8];
    const float* b2    = (const float*)d_in[9];
    const float* Wo    = (const float*)d_in[10];
    const float* bo    = (const float*)d_in[11];
    float* outp = (float*)d_out;

    const int n = NNODES;
    const int E_ = NEDGES;
    const int ET = E_ + n;

    char* ws = (char*)d_ws;
    size_t off = 0;
    auto take = [&](size_t bytes) {
        size_t p = off;
        off += (bytes + 255) & ~(size_t)255;
        return p;
    };
    float* A    = (float*)(ws + take((size_t)n * HC * 4));
    float* B    = (float*)(ws + take((size_t)n * HC * 4));
    float* al   = (float*)(ws + take((size_t)n * 3 * 4));
    float* ar   = (float*)(ws + take((size_t)n * 3 * 4));
    int* rowp   = (int*)(ws + take((size_t)(n + 1) * 4));
    int* deg    = (int*)(ws + take((size_t)n * 4));
    int* cursor = (int*)(ws + take((size_t)n * 4));
    int* esrc   = (int*)(ws + take((size_t)ET * 4));
    int* bsum   = (int*)(ws + take((size_t)SB * 4));
    int* boff   = (int*)(ws + take((size_t)SB * 4));
    (void)ws_size;
    // normalized edge weights live in d_out (5.4 MB < 8 MB); head GEMM
    // overwrites every element of d_out afterwards, so final contents are clean.
    float* wgt = (float*)d_out;

    hipMemsetAsync(deg, 0, (size_t)n * 4, stream);
    hipMemsetAsync(cursor, 0, (size_t)n * 4, stream);

    int eb = 256;
    int eg = (ET + eb - 1) / eb;
    hist_kernel<<<eg, eb, 0, stream>>>(ei, deg, E_, n);
    bsum_kernel<<<SB, 256, 0, stream>>>(deg, bsum, n);
    bscan_kernel<<<1, SB, 0, stream>>>(bsum, boff, rowp, n);
    scan_chunk_kernel<<<SB, 256, 0, stream>>>(deg, boff, rowp, n);
    scatter_kernel<<<eg, eb, 0, stream>>>(ei, rowp, cursor, esrc, E_, n);

    dim3 g1((n + 127) / 128, HC / 64);
    dim3 go((n + 127) / 128, 1);
    int nodeg4 = (n + 3) / 4;
    int nunits = n * NHEADS;
    int gatherg = (nunits + 3) / 4;

    // layer 1
    gemm_xwt<128, HC, false><<<g1, 256, 0, stream>>>(x, W1, nullptr, A, n);
    attproj_kernel<<<nodeg4, 256, 0, stream>>>(A, attl1, attr1, al, ar, n);
    weight_kernel<<<nodeg4, 256, 0, stream>>>(al, ar, rowp, esrc, wgt, n);
    gather_kernel<true><<<gatherg, 256, 0, stream>>>(A, wgt, rowp, esrc, b1, B, nunits);
    // layer 2
    gemm_xwt<HC, HC, false><<<g1, 256, 0, stream>>>(B, W2, nullptr, A, n);
    attproj_kernel<<<nodeg4, 256, 0, stream>>>(A, attl2, attr2, al, ar, n);
    weight_kernel<<<nodeg4, 256, 0, stream>>>(al, ar, rowp, esrc, wgt, n);
    gather_kernel<true><<<gatherg, 256, 0, stream>>>(A, wgt, rowp, esrc, b2, B, nunits);
    // output head
    gemm_xwt<HC, NCLS, true><<<go, 256, 0, stream>>>(B, Wo, bo, outp, n);
}

// Round 6
// 382.256 us; speedup vs baseline: 2.4402x; 1.0244x over previous
//
#include <hip/hip_runtime.h>
#include <hip/hip_bf16.h>

// GAT 2-layer + linear head. GEMM/softmax fp32; gather features bf16 (RNE).
// N=50000, E=400000 (+N self loops), IN_DIM=128, HEADS=3, HID=64 (HC=192), CLASSES=40.

#define NNODES 50000
#define NEDGES 400000
#define HC 192
#define NHEADS 3
#define HIDC 64
#define NCLS 40

// hierarchical scan geometry: 256 chunks of 196 elements cover 50176 >= N
#define SB 256
#define CHUNK 196

__device__ __forceinline__ float lrelu(float a) { return a > 0.f ? a : 0.2f * a; }

// ---------------- CSR build ----------------

__global__ void hist_kernel(const int* __restrict__ ei, int* __restrict__ deg,
                            int E_, int n) {
    int e = blockIdx.x * blockDim.x + threadIdx.x;
    int ET = E_ + n;
    if (e >= ET) return;
    int d = (e < E_) ? ei[E_ + e] : (e - E_);
    atomicAdd(&deg[d], 1);
}

// R4: single-block scan was 77us (one CU, latency-bound). 3-level scan instead.

__global__ __launch_bounds__(256) void bsum_kernel(const int* __restrict__ deg,
                                                   int* __restrict__ bsum, int n) {
    int b = blockIdx.x, t = threadIdx.x;
    int i = b * CHUNK + t;
    int v = (t < CHUNK && i < n) ? deg[i] : 0;
#pragma unroll
    for (int off = 32; off; off >>= 1) v += __shfl_xor(v, off);
    __shared__ int sh[4];
    if ((t & 63) == 0) sh[t >> 6] = v;
    __syncthreads();
    if (t == 0) bsum[b] = sh[0] + sh[1] + sh[2] + sh[3];
}

__global__ __launch_bounds__(256) void bscan_kernel(const int* __restrict__ bsum,
                                                    int* __restrict__ boff,
                                                    int* __restrict__ rowp, int n) {
    __shared__ int sh[SB];
    int t = threadIdx.x;
    int v = bsum[t];
    sh[t] = v;
    __syncthreads();
    for (int off = 1; off < SB; off <<= 1) {
        int u = (t >= off) ? sh[t - off] : 0;
        __syncthreads();
        sh[t] += u;
        __syncthreads();
    }
    boff[t] = sh[t] - v;               // exclusive
    if (t == SB - 1) rowp[n] = sh[t];  // total
}

__global__ __launch_bounds__(256) void scan_chunk_kernel(const int* __restrict__ deg,
                                                         const int* __restrict__ boff,
                                                         int* __restrict__ rowp, int n) {
    __shared__ int sh[256];
    int b = blockIdx.x, t = threadIdx.x;
    int i = b * CHUNK + t;
    int v = (t < CHUNK && i < n) ? deg[i] : 0;
    sh[t] = v;
    __syncthreads();
    for (int off = 1; off < 256; off <<= 1) {
        int u = (t >= off) ? sh[t - off] : 0;
        __syncthreads();
        sh[t] += u;
        __syncthreads();
    }
    if (t < CHUNK && i < n) rowp[i] = boff[b] + sh[t] - v;
}

__global__ void scatter_kernel(const int* __restrict__ ei, const int* __restrict__ rowp,
                               int* __restrict__ cursor, int* __restrict__ esrc,
                               int E_, int n) {
    int e = blockIdx.x * blockDim.x + threadIdx.x;
    int ET = E_ + n;
    if (e >= ET) return;
    int s, d;
    if (e < E_) { s = ei[e]; d = ei[E_ + e]; }
    else        { s = e - E_; d = s; }
    int pos = atomicAdd(&cursor[d], 1);
    esrc[rowp[d] + pos] = s;
}

// ---------------- GEMM: C[n,M] = X[n,K] @ W[M,K]^T (+bias) ----------------
// BM=128, BN=64, BK=16, 256 threads, per-thread 8x4. ~70 VGPR, 1173 blocks.

template <int K, int M, bool ADD_BIAS>
__global__ __launch_bounds__(256) void gemm_xwt(const float* __restrict__ X,
                                                const float* __restrict__ W,
                                                const float* __restrict__ bias,
                                                float* __restrict__ C, int n) {
    const int BM = 128, BN = 64, BK = 16;
    __shared__ float Xs[BK][BM + 4];
    __shared__ float Ws[BK][BN + 4];
    int bm = blockIdx.x * BM;
    int bn = blockIdx.y * BN;
    int tid = threadIdx.x;
    int tx = tid & 15;   // 16 col groups of 4
    int ty = tid >> 4;   // 16 row groups of 8
    float acc[8][4] = {};

    for (int k0 = 0; k0 < K; k0 += BK) {
#pragma unroll
        for (int t = 0; t < 2; ++t) {
            int q = tid + t * 256;
            int row = q >> 2;
            int ks = (q & 3) * 4;
            int grow = bm + row;
            float4 v = make_float4(0.f, 0.f, 0.f, 0.f);
            if (grow < n) v = *(const float4*)(X + (size_t)grow * K + k0 + ks);
            Xs[ks + 0][row] = v.x; Xs[ks + 1][row] = v.y;
            Xs[ks + 2][row] = v.z; Xs[ks + 3][row] = v.w;
        }
        {
            int rowm = tid >> 2;
            int ks = (tid & 3) * 4;
            int gm = bn + rowm;
            float4 v = make_float4(0.f, 0.f, 0.f, 0.f);
            if (gm < M) v = *(const float4*)(W + (size_t)gm * K + k0 + ks);
            Ws[ks + 0][rowm] = v.x; Ws[ks + 1][rowm] = v.y;
            Ws[ks + 2][rowm] = v.z; Ws[ks + 3][rowm] = v.w;
        }
        __syncthreads();
#pragma unroll
        for (int kk = 0; kk < BK; ++kk) {
            float4 xa = *(const float4*)&Xs[kk][ty * 8];
            float4 xb = *(const float4*)&Xs[kk][ty * 8 + 4];
            float4 wa = *(const float4*)&Ws[kk][tx * 4];
            float xr[8] = {xa.x, xa.y, xa.z, xa.w, xb.x, xb.y, xb.z, xb.w};
            float wr[4] = {wa.x, wa.y, wa.z, wa.w};
#pragma unroll
            for (int i = 0; i < 8; ++i)
#pragma unroll
                for (int j = 0; j < 4; ++j) acc[i][j] += xr[i] * wr[j];
        }
        __syncthreads();
    }
#pragma unroll
    for (int i = 0; i < 8; ++i) {
        int grow = bm + ty * 8 + i;
        if (grow >= n) continue;
        int gcol = bn + tx * 4;
        if (gcol + 3 < M) {
            float4 v;
            v.x = acc[i][0]; v.y = acc[i][1]; v.z = acc[i][2]; v.w = acc[i][3];
            if (ADD_BIAS) {
                v.x += bias[gcol + 0]; v.y += bias[gcol + 1];
                v.z += bias[gcol + 2]; v.w += bias[gcol + 3];
            }
            *(float4*)(C + (size_t)grow * M + gcol) = v;
        } else {
#pragma unroll
            for (int j = 0; j < 4; ++j) {
                int gc = gcol + j;
                if (gc < M) {
                    float v = acc[i][j];
                    if (ADD_BIAS) v += bias[gc];
                    C[(size_t)grow * M + gc] = v;
                }
            }
        }
    }
}

// ---------------- prep: al/ar projections + bf16 feature copy ----------------
// One pass over A: replaces attproj AND emits the gather operand in bf16 (RNE).

__global__ __launch_bounds__(256) void prep_kernel(const float* __restrict__ A,
                                                   const float* __restrict__ attl,
                                                   const float* __restrict__ attr,
                                                   float* __restrict__ al,
                                                   float* __restrict__ ar,
                                                   __hip_bfloat16* __restrict__ Abf,
                                                   int n) {
    int wave = threadIdx.x >> 6;
    int lane = threadIdx.x & 63;
    int node = blockIdx.x * 4 + wave;
    if (node >= n) return;
#pragma unroll
    for (int h = 0; h < NHEADS; ++h) {
        float v = A[(size_t)node * HC + h * HIDC + lane];
        Abf[(size_t)node * HC + h * HIDC + lane] = __float2bfloat16(v);
        float pl = v * attl[h * HIDC + lane];
        float pr = v * attr[h * HIDC + lane];
#pragma unroll
        for (int off = 32; off; off >>= 1) {
            pl += __shfl_xor(pl, off);
            pr += __shfl_xor(pr, off);
        }
        if (lane == 0) {
            al[node * NHEADS + h] = pl;
            ar[node * NHEADS + h] = pr;
        }
    }
}

// ---------------- edge softmax weights (normalized, fp32), wave per node ----------------

__global__ __launch_bounds__(256) void weight_kernel(const float* __restrict__ al,
                                                     const float* __restrict__ ar,
                                                     const int* __restrict__ rowp,
                                                     const int* __restrict__ esrc,
                                                     float* __restrict__ wgt, int n) {
    int node = blockIdx.x * 4 + (threadIdx.x >> 6);
    int lane = threadIdx.x & 63;
    if (node >= n) return;
    int e0 = rowp[node], e1 = rowp[node + 1];
    float ar0 = ar[node * 3 + 0], ar1 = ar[node * 3 + 1], ar2 = ar[node * 3 + 2];
    float m0 = -1e30f, m1 = -1e30f, m2 = -1e30f;
    for (int p = e0 + lane; p < e1; p += 64) {
        int s = esrc[p];
        m0 = fmaxf(m0, lrelu(al[s * 3 + 0] + ar0));
        m1 = fmaxf(m1, lrelu(al[s * 3 + 1] + ar1));
        m2 = fmaxf(m2, lrelu(al[s * 3 + 2] + ar2));
    }
#pragma unroll
    for (int off = 32; off; off >>= 1) {
        m0 = fmaxf(m0, __shfl_xor(m0, off));
        m1 = fmaxf(m1, __shfl_xor(m1, off));
        m2 = fmaxf(m2, __shfl_xor(m2, off));
    }
    float s0 = 0.f, s1 = 0.f, s2 = 0.f;
    for (int p = e0 + lane; p < e1; p += 64) {
        int s = esrc[p];
        s0 += __expf(lrelu(al[s * 3 + 0] + ar0) - m0);
        s1 += __expf(lrelu(al[s * 3 + 1] + ar1) - m1);
        s2 += __expf(lrelu(al[s * 3 + 2] + ar2) - m2);
    }
#pragma unroll
    for (int off = 32; off; off >>= 1) {
        s0 += __shfl_xor(s0, off);
        s1 += __shfl_xor(s1, off);
        s2 += __shfl_xor(s2, off);
    }
    float r0 = 1.f / (s0 + 1e-16f), r1 = 1.f / (s1 + 1e-16f), r2 = 1.f / (s2 + 1e-16f);
    for (int p = e0 + lane; p < e1; p += 64) {
        int s = esrc[p];
        wgt[p * 3 + 0] = __expf(lrelu(al[s * 3 + 0] + ar0) - m0) * r0;
        wgt[p * 3 + 1] = __expf(lrelu(al[s * 3 + 1] + ar1) - m1) * r1;
        wgt[p * 3 + 2] = __expf(lrelu(al[s * 3 + 2] + ar2) - m2) * r2;
    }
}

// ---------------- gather: wave per (node, head); 4 edge-groups x 16 lanes ----------------
// bf16 features: 16 lanes x ushort4(8B) = one 128B head-slice per edge (1 cache line,
// was 2 with fp32). fp32 weights and accumulation.

template <bool RELU>
__global__ __launch_bounds__(256) void gather_kernel(const __hip_bfloat16* __restrict__ hfeat,
                                                     const float* __restrict__ wgt,
                                                     const int* __restrict__ rowp,
                                                     const int* __restrict__ esrc,
                                                     const float* __restrict__ bias,
                                                     float* __restrict__ out, int nunits) {
    int unit = blockIdx.x * 4 + (threadIdx.x >> 6);
    if (unit >= nunits) return;
    int node = unit / 3;
    int head = unit - node * 3;
    int lane = threadIdx.x & 63;
    int g = lane >> 4;        // edge group 0..3
    int c4 = lane & 15;       // ushort4 slot within the 64-elem head row
    int e0 = rowp[node], e1 = rowp[node + 1];
    const __hip_bfloat16* base = hfeat + (size_t)head * HIDC + c4 * 4;

    float4 acc = make_float4(0.f, 0.f, 0.f, 0.f);
    int e = e0 + g;
    for (; e + 4 < e1; e += 8) {
        int s0 = esrc[e];
        int s1 = esrc[e + 4];
        float w0 = wgt[e * 3 + head];
        float w1 = wgt[(e + 4) * 3 + head];
        ushort4 u0 = *(const ushort4*)(base + (size_t)s0 * HC);
        ushort4 u1 = *(const ushort4*)(base + (size_t)s1 * HC);
        acc.x += w0 * __uint_as_float((unsigned)u0.x << 16) + w1 * __uint_as_float((unsigned)u1.x << 16);
        acc.y += w0 * __uint_as_float((unsigned)u0.y << 16) + w1 * __uint_as_float((unsigned)u1.y << 16);
        acc.z += w0 * __uint_as_float((unsigned)u0.z << 16) + w1 * __uint_as_float((unsigned)u1.z << 16);
        acc.w += w0 * __uint_as_float((unsigned)u0.w << 16) + w1 * __uint_as_float((unsigned)u1.w << 16);
    }
    if (e < e1) {
        int s0 = esrc[e];
        float w0 = wgt[e * 3 + head];
        ushort4 u0 = *(const ushort4*)(base + (size_t)s0 * HC);
        acc.x += w0 * __uint_as_float((unsigned)u0.x << 16);
        acc.y += w0 * __uint_as_float((unsigned)u0.y << 16);
        acc.z += w0 * __uint_as_float((unsigned)u0.z << 16);
        acc.w += w0 * __uint_as_float((unsigned)u0.w << 16);
    }
#pragma unroll
    for (int off = 16; off <= 32; off <<= 1) {
        acc.x += __shfl_xor(acc.x, off);
        acc.y += __shfl_xor(acc.y, off);
        acc.z += __shfl_xor(acc.z, off);
        acc.w += __shfl_xor(acc.w, off);
    }
    if (g == 0) {
        const float4 bv = *(const float4*)(bias + head * HIDC + c4 * 4);
        float4 v;
        v.x = acc.x + bv.x; v.y = acc.y + bv.y;
        v.z = acc.z + bv.z; v.w = acc.w + bv.w;
        if (RELU) {
            v.x = fmaxf(v.x, 0.f); v.y = fmaxf(v.y, 0.f);
            v.z = fmaxf(v.z, 0.f); v.w = fmaxf(v.w, 0.f);
        }
        *(float4*)(out + (size_t)node * HC + head * HIDC + c4 * 4) = v;
    }
}

// ---------------- launch ----------------

extern "C" void kernel_launch(void* const* d_in, const int* in_sizes, int n_in,
                              void* d_out, int out_size, void* d_ws, size_t ws_size,
                              hipStream_t stream) {
    const float* x     = (const float*)d_in[0];
    const int*   ei    = (const int*)d_in[1];   // [2,E] int
    const float* W1    = (const float*)d_in[2];
    const float* attl1 = (const float*)d_in[3];
    const float* attr1 = (const float*)d_in[4];
    const float* b1    = (const float*)d_in[5];
    const float* W2    = (const float*)d_in[6];
    const float* attl2 = (const float*)d_in[7];
    const float* attr2 = (const float*)d_in[8];
    const float* b2    = (const float*)d_in[9];
    const float* Wo    = (const float*)d_in[10];
    const float* bo    = (const float*)d_in[11];
    float* outp = (float*)d_out;

    const int n = NNODES;
    const int E_ = NEDGES;
    const int ET = E_ + n;

    char* ws = (char*)d_ws;
    size_t off = 0;
    auto take = [&](size_t bytes) {
        size_t p = off;
        off += (bytes + 255) & ~(size_t)255;
        return p;
    };
    float* A    = (float*)(ws + take((size_t)n * HC * 4));
    float* B    = (float*)(ws + take((size_t)n * HC * 4));
    __hip_bfloat16* Abf = (__hip_bfloat16*)(ws + take((size_t)n * HC * 2));
    float* al   = (float*)(ws + take((size_t)n * 3 * 4));
    float* ar   = (float*)(ws + take((size_t)n * 3 * 4));
    int* rowp   = (int*)(ws + take((size_t)(n + 1) * 4));
    int* deg    = (int*)(ws + take((size_t)n * 4));
    int* cursor = (int*)(ws + take((size_t)n * 4));
    int* esrc   = (int*)(ws + take((size_t)ET * 4));
    int* bsum   = (int*)(ws + take((size_t)SB * 4));
    int* boff   = (int*)(ws + take((size_t)SB * 4));
    (void)ws_size;
    // normalized edge weights live in d_out (5.4 MB < 8 MB); head GEMM
    // overwrites every element of d_out afterwards, so final contents are clean.
    float* wgt = (float*)d_out;

    hipMemsetAsync(deg, 0, (size_t)n * 4, stream);
    hipMemsetAsync(cursor, 0, (size_t)n * 4, stream);

    int eb = 256;
    int eg = (ET + eb - 1) / eb;
    hist_kernel<<<eg, eb, 0, stream>>>(ei, deg, E_, n);
    bsum_kernel<<<SB, 256, 0, stream>>>(deg, bsum, n);
    bscan_kernel<<<1, SB, 0, stream>>>(bsum, boff, rowp, n);
    scan_chunk_kernel<<<SB, 256, 0, stream>>>(deg, boff, rowp, n);
    scatter_kernel<<<eg, eb, 0, stream>>>(ei, rowp, cursor, esrc, E_, n);

    dim3 g1((n + 127) / 128, HC / 64);
    dim3 go((n + 127) / 128, 1);
    int nodeg4 = (n + 3) / 4;
    int nunits = n * NHEADS;
    int gatherg = (nunits + 3) / 4;

    // layer 1
    gemm_xwt<128, HC, false><<<g1, 256, 0, stream>>>(x, W1, nullptr, A, n);
    prep_kernel<<<nodeg4, 256, 0, stream>>>(A, attl1, attr1, al, ar, Abf, n);
    weight_kernel<<<nodeg4, 256, 0, stream>>>(al, ar, rowp, esrc, wgt, n);
    gather_kernel<true><<<gatherg, 256, 0, stream>>>(Abf, wgt, rowp, esrc, b1, B, nunits);
    // layer 2
    gemm_xwt<HC, HC, false><<<g1, 256, 0, stream>>>(B, W2, nullptr, A, n);
    prep_kernel<<<nodeg4, 256, 0, stream>>>(A, attl2, attr2, al, ar, Abf, n);
    weight_kernel<<<nodeg4, 256, 0, stream>>>(al, ar, rowp, esrc, wgt, n);
    gather_kernel<true><<<gatherg, 256, 0, stream>>>(Abf, wgt, rowp, esrc, b2, B, nunits);
    // output head
    gemm_xwt<HC, NCLS, true><<<go, 256, 0, stream>>>(B, Wo, bo, outp, n);
}

// Round 7
// 331.763 us; speedup vs baseline: 2.8115x; 1.1522x over previous
//
#include <hip/hip_runtime.h>
#include <hip/hip_bf16.h>

// GAT 2-layer + linear head.
// Layer GEMMs: bf16 MFMA (fp32 accum). Head GEMM + softmax: fp32. Gather: bf16 feats.
// N=50000, E=400000 (+N self loops), IN_DIM=128, HEADS=3, HID=64 (HC=192), CLASSES=40.

#define NNODES 50000
#define NEDGES 400000
#define HC 192
#define NHEADS 3
#define HIDC 64
#define NCLS 40

#define SB 256
#define CHUNK 196

typedef __attribute__((ext_vector_type(8))) short bf16x8;
typedef __attribute__((ext_vector_type(4))) float f32x4;

__device__ __forceinline__ float lrelu(float a) { return a > 0.f ? a : 0.2f * a; }
__device__ __forceinline__ float bf2f(unsigned short u) {
    return __uint_as_float((unsigned)u << 16);
}
__device__ __forceinline__ unsigned short f2bf(float f) {
    __hip_bfloat16 b = __float2bfloat16(f);
    return *(unsigned short*)&b;
}

// ---------------- bf16 casts ----------------

__global__ void cast_bf16_kernel(const float* __restrict__ src,
                                 unsigned short* __restrict__ dst, int count4) {
    int i = blockIdx.x * blockDim.x + threadIdx.x;
    int stride = gridDim.x * blockDim.x;
    for (; i < count4; i += stride) {
        float4 v = ((const float4*)src)[i];
        ushort4 u;
        u.x = f2bf(v.x); u.y = f2bf(v.y); u.z = f2bf(v.z); u.w = f2bf(v.w);
        ((ushort4*)dst)[i] = u;
    }
}

// ---------------- CSR build ----------------

__global__ void hist_kernel(const int* __restrict__ ei, int* __restrict__ deg,
                            int E_, int n) {
    int e = blockIdx.x * blockDim.x + threadIdx.x;
    int ET = E_ + n;
    if (e >= ET) return;
    int d = (e < E_) ? ei[E_ + e] : (e - E_);
    atomicAdd(&deg[d], 1);
}

__global__ __launch_bounds__(256) void bsum_kernel(const int* __restrict__ deg,
                                                   int* __restrict__ bsum, int n) {
    int b = blockIdx.x, t = threadIdx.x;
    int i = b * CHUNK + t;
    int v = (t < CHUNK && i < n) ? deg[i] : 0;
#pragma unroll
    for (int off = 32; off; off >>= 1) v += __shfl_xor(v, off);
    __shared__ int sh[4];
    if ((t & 63) == 0) sh[t >> 6] = v;
    __syncthreads();
    if (t == 0) bsum[b] = sh[0] + sh[1] + sh[2] + sh[3];
}

__global__ __launch_bounds__(256) void bscan_kernel(const int* __restrict__ bsum,
                                                    int* __restrict__ boff,
                                                    int* __restrict__ rowp, int n) {
    __shared__ int sh[SB];
    int t = threadIdx.x;
    int v = bsum[t];
    sh[t] = v;
    __syncthreads();
    for (int off = 1; off < SB; off <<= 1) {
        int u = (t >= off) ? sh[t - off] : 0;
        __syncthreads();
        sh[t] += u;
        __syncthreads();
    }
    boff[t] = sh[t] - v;
    if (t == SB - 1) rowp[n] = sh[t];
}

__global__ __launch_bounds__(256) void scan_chunk_kernel(const int* __restrict__ deg,
                                                         const int* __restrict__ boff,
                                                         int* __restrict__ rowp, int n) {
    __shared__ int sh[256];
    int b = blockIdx.x, t = threadIdx.x;
    int i = b * CHUNK + t;
    int v = (t < CHUNK && i < n) ? deg[i] : 0;
    sh[t] = v;
    __syncthreads();
    for (int off = 1; off < 256; off <<= 1) {
        int u = (t >= off) ? sh[t - off] : 0;
        __syncthreads();
        sh[t] += u;
        __syncthreads();
    }
    if (t < CHUNK && i < n) rowp[i] = boff[b] + sh[t] - v;
}

__global__ void scatter_kernel(const int* __restrict__ ei, const int* __restrict__ rowp,
                               int* __restrict__ cursor, int* __restrict__ esrc,
                               int E_, int n) {
    int e = blockIdx.x * blockDim.x + threadIdx.x;
    int ET = E_ + n;
    if (e >= ET) return;
    int s, d;
    if (e < E_) { s = ei[e]; d = ei[E_ + e]; }
    else        { s = e - E_; d = s; }
    int pos = atomicAdd(&cursor[d], 1);
    esrc[rowp[d] + pos] = s;
}

// ---------------- MFMA GEMM: C[n,192] = Xbf[n,K] @ Wbf[192,K]^T (fp32 out) ----------------
// 192 threads = 3 waves; wave computes 32 rows x 96-col W panel; 2 panels.
// W panel staged in LDS (<=37KB), XOR-swizzled (kb^(row&7)) -> 2-way bank = free.
// A-frags direct from global (X read twice; bf16 X is L3-resident).
// mfma_f32_16x16x32_bf16: A row=l&15,k=(l>>4)*8+j ; C col=l&15,row=(l>>4)*4+reg [m89].

template <int K>
__global__ __launch_bounds__(192) void gemm_mfma(const unsigned short* __restrict__ X,
                                                 const unsigned short* __restrict__ Wb,
                                                 float* __restrict__ C, int n) {
    constexpr int UNITS = K / 8;          // 16B units per W row
    __shared__ char smem[96 * K * 2];     // one 96-row W panel, swizzled
    int tid = threadIdx.x;
    int wave = tid >> 6, lane = tid & 63;
    int r16 = lane & 15;                  // A-row / C-col selector
    int hi = lane >> 4;                   // k-group 0..3 / C-row group
    int bm = blockIdx.x * 96 + wave * 32;

#pragma unroll
    for (int p = 0; p < 2; ++p) {
        // stage W rows [p*96, p*96+96) into LDS, swizzled
        for (int u = tid; u < 96 * UNITS; u += 192) {
            int row = u / UNITS, kb = u % UNITS;
            uint4 v = *(const uint4*)(Wb + ((size_t)(p * 96 + row) * K + kb * 8));
            *(uint4*)(smem + ((size_t)row * UNITS + (kb ^ (row & 7))) * 16) = v;
        }
        __syncthreads();

        f32x4 acc[6][2];
#pragma unroll
        for (int j = 0; j < 6; ++j)
#pragma unroll
            for (int r = 0; r < 2; ++r) acc[j][r] = (f32x4){0.f, 0.f, 0.f, 0.f};

#pragma unroll
        for (int ks = 0; ks < K / 32; ++ks) {
            bf16x8 a0 = {}, a1 = {};
            int row0 = bm + r16;
            int row1 = bm + 16 + r16;
            if (row0 < n) a0 = *(const bf16x8*)(X + (size_t)row0 * K + ks * 32 + hi * 8);
            if (row1 < n) a1 = *(const bf16x8*)(X + (size_t)row1 * K + ks * 32 + hi * 8);
#pragma unroll
            for (int j = 0; j < 6; ++j) {
                int wl = j * 16 + r16;
                int kb = ks * 4 + hi;
                bf16x8 b = *(const bf16x8*)(smem + ((size_t)wl * UNITS + (kb ^ (wl & 7))) * 16);
                acc[j][0] = __builtin_amdgcn_mfma_f32_16x16x32_bf16(a0, b, acc[j][0], 0, 0, 0);
                acc[j][1] = __builtin_amdgcn_mfma_f32_16x16x32_bf16(a1, b, acc[j][1], 0, 0, 0);
            }
        }

        // write panel cols
#pragma unroll
        for (int j = 0; j < 6; ++j)
#pragma unroll
            for (int r = 0; r < 2; ++r)
#pragma unroll
                for (int q = 0; q < 4; ++q) {
                    int row = bm + r * 16 + hi * 4 + q;
                    if (row < n) C[(size_t)row * HC + p * 96 + j * 16 + r16] = acc[j][r][q];
                }
        __syncthreads();  // before restaging next panel
    }
}

// ---------------- head GEMM (fp32): out[n,40] = B[n,192] @ Wo[40,192]^T + bo ----------------

template <int K, int M, bool ADD_BIAS>
__global__ __launch_bounds__(256) void gemm_xwt(const float* __restrict__ X,
                                                const float* __restrict__ W,
                                                const float* __restrict__ bias,
                                                float* __restrict__ C, int n) {
    const int BM = 128, BN = 64, BK = 16;
    __shared__ float Xs[BK][BM + 4];
    __shared__ float Ws[BK][BN + 4];
    int bm = blockIdx.x * BM;
    int bn = blockIdx.y * BN;
    int tid = threadIdx.x;
    int tx = tid & 15;
    int ty = tid >> 4;
    float acc[8][4] = {};

    for (int k0 = 0; k0 < K; k0 += BK) {
#pragma unroll
        for (int t = 0; t < 2; ++t) {
            int q = tid + t * 256;
            int row = q >> 2;
            int ks = (q & 3) * 4;
            int grow = bm + row;
            float4 v = make_float4(0.f, 0.f, 0.f, 0.f);
            if (grow < n) v = *(const float4*)(X + (size_t)grow * K + k0 + ks);
            Xs[ks + 0][row] = v.x; Xs[ks + 1][row] = v.y;
            Xs[ks + 2][row] = v.z; Xs[ks + 3][row] = v.w;
        }
        {
            int rowm = tid >> 2;
            int ks = (tid & 3) * 4;
            int gm = bn + rowm;
            float4 v = make_float4(0.f, 0.f, 0.f, 0.f);
            if (gm < M) v = *(const float4*)(W + (size_t)gm * K + k0 + ks);
            Ws[ks + 0][rowm] = v.x; Ws[ks + 1][rowm] = v.y;
            Ws[ks + 2][rowm] = v.z; Ws[ks + 3][rowm] = v.w;
        }
        __syncthreads();
#pragma unroll
        for (int kk = 0; kk < BK; ++kk) {
            float4 xa = *(const float4*)&Xs[kk][ty * 8];
            float4 xb = *(const float4*)&Xs[kk][ty * 8 + 4];
            float4 wa = *(const float4*)&Ws[kk][tx * 4];
            float xr[8] = {xa.x, xa.y, xa.z, xa.w, xb.x, xb.y, xb.z, xb.w};
            float wr[4] = {wa.x, wa.y, wa.z, wa.w};
#pragma unroll
            for (int i = 0; i < 8; ++i)
#pragma unroll
                for (int j = 0; j < 4; ++j) acc[i][j] += xr[i] * wr[j];
        }
        __syncthreads();
    }
#pragma unroll
    for (int i = 0; i < 8; ++i) {
        int grow = bm + ty * 8 + i;
        if (grow >= n) continue;
        int gcol = bn + tx * 4;
        if (gcol + 3 < M) {
            float4 v;
            v.x = acc[i][0]; v.y = acc[i][1]; v.z = acc[i][2]; v.w = acc[i][3];
            if (ADD_BIAS) {
                v.x += bias[gcol + 0]; v.y += bias[gcol + 1];
                v.z += bias[gcol + 2]; v.w += bias[gcol + 3];
            }
            *(float4*)(C + (size_t)grow * M + gcol) = v;
        } else {
#pragma unroll
            for (int j = 0; j < 4; ++j) {
                int gc = gcol + j;
                if (gc < M) {
                    float v = acc[i][j];
                    if (ADD_BIAS) v += bias[gc];
                    C[(size_t)grow * M + gc] = v;
                }
            }
        }
    }
}

// ---------------- prep: al/ar projections + bf16 feature copy ----------------

__global__ __launch_bounds__(256) void prep_kernel(const float* __restrict__ A,
                                                   const float* __restrict__ attl,
                                                   const float* __restrict__ attr,
                                                   float* __restrict__ al,
                                                   float* __restrict__ ar,
                                                   unsigned short* __restrict__ Abf,
                                                   int n) {
    int wave = threadIdx.x >> 6;
    int lane = threadIdx.x & 63;
    int node = blockIdx.x * 4 + wave;
    if (node >= n) return;
#pragma unroll
    for (int h = 0; h < NHEADS; ++h) {
        float v = A[(size_t)node * HC + h * HIDC + lane];
        Abf[(size_t)node * HC + h * HIDC + lane] = f2bf(v);
        float pl = v * attl[h * HIDC + lane];
        float pr = v * attr[h * HIDC + lane];
#pragma unroll
        for (int off = 32; off; off >>= 1) {
            pl += __shfl_xor(pl, off);
            pr += __shfl_xor(pr, off);
        }
        if (lane == 0) {
            al[node * NHEADS + h] = pl;
            ar[node * NHEADS + h] = pr;
        }
    }
}

// ---------------- edge softmax weights (normalized, fp32) ----------------

__global__ __launch_bounds__(256) void weight_kernel(const float* __restrict__ al,
                                                     const float* __restrict__ ar,
                                                     const int* __restrict__ rowp,
                                                     const int* __restrict__ esrc,
                                                     float* __restrict__ wgt, int n) {
    int node = blockIdx.x * 4 + (threadIdx.x >> 6);
    int lane = threadIdx.x & 63;
    if (node >= n) return;
    int e0 = rowp[node], e1 = rowp[node + 1];
    float ar0 = ar[node * 3 + 0], ar1 = ar[node * 3 + 1], ar2 = ar[node * 3 + 2];
    float m0 = -1e30f, m1 = -1e30f, m2 = -1e30f;
    for (int p = e0 + lane; p < e1; p += 64) {
        int s = esrc[p];
        m0 = fmaxf(m0, lrelu(al[s * 3 + 0] + ar0));
        m1 = fmaxf(m1, lrelu(al[s * 3 + 1] + ar1));
        m2 = fmaxf(m2, lrelu(al[s * 3 + 2] + ar2));
    }
#pragma unroll
    for (int off = 32; off; off >>= 1) {
        m0 = fmaxf(m0, __shfl_xor(m0, off));
        m1 = fmaxf(m1, __shfl_xor(m1, off));
        m2 = fmaxf(m2, __shfl_xor(m2, off));
    }
    float s0 = 0.f, s1 = 0.f, s2 = 0.f;
    for (int p = e0 + lane; p < e1; p += 64) {
        int s = esrc[p];
        s0 += __expf(lrelu(al[s * 3 + 0] + ar0) - m0);
        s1 += __expf(lrelu(al[s * 3 + 1] + ar1) - m1);
        s2 += __expf(lrelu(al[s * 3 + 2] + ar2) - m2);
    }
#pragma unroll
    for (int off = 32; off; off >>= 1) {
        s0 += __shfl_xor(s0, off);
        s1 += __shfl_xor(s1, off);
        s2 += __shfl_xor(s2, off);
    }
    float r0 = 1.f / (s0 + 1e-16f), r1 = 1.f / (s1 + 1e-16f), r2 = 1.f / (s2 + 1e-16f);
    for (int p = e0 + lane; p < e1; p += 64) {
        int s = esrc[p];
        wgt[p * 3 + 0] = __expf(lrelu(al[s * 3 + 0] + ar0) - m0) * r0;
        wgt[p * 3 + 1] = __expf(lrelu(al[s * 3 + 1] + ar1) - m1) * r1;
        wgt[p * 3 + 2] = __expf(lrelu(al[s * 3 + 2] + ar2) - m2) * r2;
    }
}

// ---------------- gather: wave per (node, head); 4 edge-groups x 16 lanes ----------------
// bf16 features in; fp32 accumulate; output fp32 or bf16 (layer-1 feeds MFMA GEMM2).

template <bool RELU, bool OUT_BF16>
__global__ __launch_bounds__(256) void gather_kernel(const unsigned short* __restrict__ hfeat,
                                                     const float* __restrict__ wgt,
                                                     const int* __restrict__ rowp,
                                                     const int* __restrict__ esrc,
                                                     const float* __restrict__ bias,
                                                     void* __restrict__ outv, int nunits) {
    int unit = blockIdx.x * 4 + (threadIdx.x >> 6);
    if (unit >= nunits) return;
    int node = unit / 3;
    int head = unit - node * 3;
    int lane = threadIdx.x & 63;
    int g = lane >> 4;
    int c4 = lane & 15;
    int e0 = rowp[node], e1 = rowp[node + 1];
    const unsigned short* base = hfeat + (size_t)head * HIDC + c4 * 4;

    float4 acc = make_float4(0.f, 0.f, 0.f, 0.f);
    int e = e0 + g;
    for (; e + 4 < e1; e += 8) {
        int s0 = esrc[e];
        int s1 = esrc[e + 4];
        float w0 = wgt[e * 3 + head];
        float w1 = wgt[(e + 4) * 3 + head];
        ushort4 u0 = *(const ushort4*)(base + (size_t)s0 * HC);
        ushort4 u1 = *(const ushort4*)(base + (size_t)s1 * HC);
        acc.x += w0 * bf2f(u0.x) + w1 * bf2f(u1.x);
        acc.y += w0 * bf2f(u0.y) + w1 * bf2f(u1.y);
        acc.z += w0 * bf2f(u0.z) + w1 * bf2f(u1.z);
        acc.w += w0 * bf2f(u0.w) + w1 * bf2f(u1.w);
    }
    if (e < e1) {
        int s0 = esrc[e];
        float w0 = wgt[e * 3 + head];
        ushort4 u0 = *(const ushort4*)(base + (size_t)s0 * HC);
        acc.x += w0 * bf2f(u0.x);
        acc.y += w0 * bf2f(u0.y);
        acc.z += w0 * bf2f(u0.z);
        acc.w += w0 * bf2f(u0.w);
    }
#pragma unroll
    for (int off = 16; off <= 32; off <<= 1) {
        acc.x += __shfl_xor(acc.x, off);
        acc.y += __shfl_xor(acc.y, off);
        acc.z += __shfl_xor(acc.z, off);
        acc.w += __shfl_xor(acc.w, off);
    }
    if (g == 0) {
        const float4 bv = *(const float4*)(bias + head * HIDC + c4 * 4);
        float4 v;
        v.x = acc.x + bv.x; v.y = acc.y + bv.y;
        v.z = acc.z + bv.z; v.w = acc.w + bv.w;
        if (RELU) {
            v.x = fmaxf(v.x, 0.f); v.y = fmaxf(v.y, 0.f);
            v.z = fmaxf(v.z, 0.f); v.w = fmaxf(v.w, 0.f);
        }
        size_t idx = (size_t)node * HC + head * HIDC + c4 * 4;
        if (OUT_BF16) {
            ushort4 u;
            u.x = f2bf(v.x); u.y = f2bf(v.y); u.z = f2bf(v.z); u.w = f2bf(v.w);
            *(ushort4*)((unsigned short*)outv + idx) = u;
        } else {
            *(float4*)((float*)outv + idx) = v;
        }
    }
}

// ---------------- launch ----------------

extern "C" void kernel_launch(void* const* d_in, const int* in_sizes, int n_in,
                              void* d_out, int out_size, void* d_ws, size_t ws_size,
                              hipStream_t stream) {
    const float* x     = (const float*)d_in[0];
    const int*   ei    = (const int*)d_in[1];
    const float* W1    = (const float*)d_in[2];
    const float* attl1 = (const float*)d_in[3];
    const float* attr1 = (const float*)d_in[4];
    const float* b1    = (const float*)d_in[5];
    const float* W2    = (const float*)d_in[6];
    const float* attl2 = (const float*)d_in[7];
    const float* attr2 = (const float*)d_in[8];
    const float* b2    = (const float*)d_in[9];
    const float* Wo    = (const float*)d_in[10];
    const float* bo    = (const float*)d_in[11];
    float* outp = (float*)d_out;

    const int n = NNODES;
    const int E_ = NEDGES;
    const int ET = E_ + n;

    char* ws = (char*)d_ws;
    size_t off = 0;
    auto take = [&](size_t bytes) {
        size_t p = off;
        off += (bytes + 255) & ~(size_t)255;
        return p;
    };
    float* A            = (float*)(ws + take((size_t)n * HC * 4));          // gemm out / gather2 out
    unsigned short* Abf = (unsigned short*)(ws + take((size_t)n * HC * 2)); // prep bf16 feats
    unsigned short* Bbf = (unsigned short*)(ws + take((size_t)n * HC * 2)); // gather1 bf16 out
    unsigned short* xbf = (unsigned short*)(ws + take((size_t)n * 128 * 2));
    unsigned short* W1bf = (unsigned short*)(ws + take((size_t)HC * 128 * 2));
    unsigned short* W2bf = (unsigned short*)(ws + take((size_t)HC * HC * 2));
    float* al   = (float*)(ws + take((size_t)n * 3 * 4));
    float* ar   = (float*)(ws + take((size_t)n * 3 * 4));
    int* rowp   = (int*)(ws + take((size_t)(n + 1) * 4));
    int* deg    = (int*)(ws + take((size_t)n * 4));
    int* cursor = (int*)(ws + take((size_t)n * 4));
    int* esrc   = (int*)(ws + take((size_t)ET * 4));
    int* bsum   = (int*)(ws + take((size_t)SB * 4));
    int* boff   = (int*)(ws + take((size_t)SB * 4));
    (void)ws_size;
    float* wgt = (float*)d_out;  // overwritten by head GEMM afterwards

    hipMemsetAsync(deg, 0, (size_t)n * 4, stream);
    hipMemsetAsync(cursor, 0, (size_t)n * 4, stream);

    // bf16 casts
    int xc4 = n * 128 / 4;
    cast_bf16_kernel<<<2048, 256, 0, stream>>>(x, xbf, xc4);
    cast_bf16_kernel<<<(HC * 128 / 4 + 255) / 256, 256, 0, stream>>>(W1, W1bf, HC * 128 / 4);
    cast_bf16_kernel<<<(HC * HC / 4 + 255) / 256, 256, 0, stream>>>(W2, W2bf, HC * HC / 4);

    int eb = 256;
    int eg = (ET + eb - 1) / eb;
    hist_kernel<<<eg, eb, 0, stream>>>(ei, deg, E_, n);
    bsum_kernel<<<SB, 256, 0, stream>>>(deg, bsum, n);
    bscan_kernel<<<1, SB, 0, stream>>>(bsum, boff, rowp, n);
    scan_chunk_kernel<<<SB, 256, 0, stream>>>(deg, boff, rowp, n);
    scatter_kernel<<<eg, eb, 0, stream>>>(ei, rowp, cursor, esrc, E_, n);

    int mfma_grid = (n + 95) / 96;
    dim3 go((n + 127) / 128, 1);
    int nodeg4 = (n + 3) / 4;
    int nunits = n * NHEADS;
    int gatherg = (nunits + 3) / 4;

    // layer 1
    gemm_mfma<128><<<mfma_grid, 192, 0, stream>>>(xbf, W1bf, A, n);
    prep_kernel<<<nodeg4, 256, 0, stream>>>(A, attl1, attr1, al, ar, Abf, n);
    weight_kernel<<<nodeg4, 256, 0, stream>>>(al, ar, rowp, esrc, wgt, n);
    gather_kernel<true, true><<<gatherg, 256, 0, stream>>>(Abf, wgt, rowp, esrc, b1, Bbf, nunits);
    // layer 2
    gemm_mfma<192><<<mfma_grid, 192, 0, stream>>>(Bbf, W2bf, A, n);
    prep_kernel<<<nodeg4, 256, 0, stream>>>(A, attl2, attr2, al, ar, Abf, n);
    weight_kernel<<<nodeg4, 256, 0, stream>>>(al, ar, rowp, esrc, wgt, n);
    gather_kernel<true, false><<<gatherg, 256, 0, stream>>>(Abf, wgt, rowp, esrc, b2, A, nunits);
    // output head (fp32)
    gemm_xwt<HC, NCLS, true><<<go, 256, 0, stream>>>(A, Wo, bo, outp, n);
}

// Round 8
// 291.388 us; speedup vs baseline: 3.2011x; 1.1386x over previous
//
#include <hip/hip_runtime.h>
#include <hip/hip_bf16.h>

// GAT 2-layer + linear head.
// Layer GEMMs: bf16 MFMA (fp32 accum). Head GEMM + softmax: fp32. Gather: bf16 feats.
// N=50000, E=400000 (+N self loops), IN_DIM=128, HEADS=3, HID=64 (HC=192), CLASSES=40.

#define NNODES 50000
#define NEDGES 400000
#define HC 192
#define NHEADS 3
#define HIDC 64
#define NCLS 40

#define SB 256
#define CHUNK 196

typedef __attribute__((ext_vector_type(8))) short bf16x8;
typedef __attribute__((ext_vector_type(4))) float f32x4;

__device__ __forceinline__ float lrelu(float a) { return a > 0.f ? a : 0.2f * a; }
__device__ __forceinline__ float bf2f(unsigned short u) {
    return __uint_as_float((unsigned)u << 16);
}
__device__ __forceinline__ unsigned short f2bf(float f) {
    __hip_bfloat16 b = __float2bfloat16(f);
    return *(unsigned short*)&b;
}

// ---------------- bf16 casts ----------------

__global__ void cast_bf16_kernel(const float* __restrict__ src,
                                 unsigned short* __restrict__ dst, int count4) {
    int i = blockIdx.x * blockDim.x + threadIdx.x;
    int stride = gridDim.x * blockDim.x;
    for (; i < count4; i += stride) {
        float4 v = ((const float4*)src)[i];
        ushort4 u;
        u.x = f2bf(v.x); u.y = f2bf(v.y); u.z = f2bf(v.z); u.w = f2bf(v.w);
        ((ushort4*)dst)[i] = u;
    }
}

// ---------------- CSR build ----------------

__global__ void hist_kernel(const int* __restrict__ ei, int* __restrict__ deg,
                            int E_, int n) {
    int e = blockIdx.x * blockDim.x + threadIdx.x;
    int ET = E_ + n;
    if (e >= ET) return;
    int d = (e < E_) ? ei[E_ + e] : (e - E_);
    atomicAdd(&deg[d], 1);
}

__global__ __launch_bounds__(256) void bsum_kernel(const int* __restrict__ deg,
                                                   int* __restrict__ bsum, int n) {
    int b = blockIdx.x, t = threadIdx.x;
    int i = b * CHUNK + t;
    int v = (t < CHUNK && i < n) ? deg[i] : 0;
#pragma unroll
    for (int off = 32; off; off >>= 1) v += __shfl_xor(v, off);
    __shared__ int sh[4];
    if ((t & 63) == 0) sh[t >> 6] = v;
    __syncthreads();
    if (t == 0) bsum[b] = sh[0] + sh[1] + sh[2] + sh[3];
}

__global__ __launch_bounds__(256) void bscan_kernel(const int* __restrict__ bsum,
                                                    int* __restrict__ boff,
                                                    int* __restrict__ rowp, int n) {
    __shared__ int sh[SB];
    int t = threadIdx.x;
    int v = bsum[t];
    sh[t] = v;
    __syncthreads();
    for (int off = 1; off < SB; off <<= 1) {
        int u = (t >= off) ? sh[t - off] : 0;
        __syncthreads();
        sh[t] += u;
        __syncthreads();
    }
    boff[t] = sh[t] - v;
    if (t == SB - 1) rowp[n] = sh[t];
}

__global__ __launch_bounds__(256) void scan_chunk_kernel(const int* __restrict__ deg,
                                                         const int* __restrict__ boff,
                                                         int* __restrict__ rowp, int n) {
    __shared__ int sh[256];
    int b = blockIdx.x, t = threadIdx.x;
    int i = b * CHUNK + t;
    int v = (t < CHUNK && i < n) ? deg[i] : 0;
    sh[t] = v;
    __syncthreads();
    for (int off = 1; off < 256; off <<= 1) {
        int u = (t >= off) ? sh[t - off] : 0;
        __syncthreads();
        sh[t] += u;
        __syncthreads();
    }
    if (t < CHUNK && i < n) rowp[i] = boff[b] + sh[t] - v;
}

__global__ void scatter_kernel(const int* __restrict__ ei, const int* __restrict__ rowp,
                               int* __restrict__ cursor, int* __restrict__ esrc,
                               int E_, int n) {
    int e = blockIdx.x * blockDim.x + threadIdx.x;
    int ET = E_ + n;
    if (e >= ET) return;
    int s, d;
    if (e < E_) { s = ei[e]; d = ei[E_ + e]; }
    else        { s = e - E_; d = s; }
    int pos = atomicAdd(&cursor[d], 1);
    esrc[rowp[d] + pos] = s;
}

// ---------------- MFMA GEMM: C[n,192] = Xbf[n,K] @ Wbf[192,K]^T (fp32 out) ----------------

template <int K>
__global__ __launch_bounds__(192) void gemm_mfma(const unsigned short* __restrict__ X,
                                                 const unsigned short* __restrict__ Wb,
                                                 float* __restrict__ C, int n) {
    constexpr int UNITS = K / 8;          // 16B units per W row
    __shared__ char smem[96 * K * 2];     // one 96-row W panel, swizzled
    int tid = threadIdx.x;
    int wave = tid >> 6, lane = tid & 63;
    int r16 = lane & 15;
    int hi = lane >> 4;
    int bm = blockIdx.x * 96 + wave * 32;

#pragma unroll
    for (int p = 0; p < 2; ++p) {
        for (int u = tid; u < 96 * UNITS; u += 192) {
            int row = u / UNITS, kb = u % UNITS;
            uint4 v = *(const uint4*)(Wb + ((size_t)(p * 96 + row) * K + kb * 8));
            *(uint4*)(smem + ((size_t)row * UNITS + (kb ^ (row & 7))) * 16) = v;
        }
        __syncthreads();

        f32x4 acc[6][2];
#pragma unroll
        for (int j = 0; j < 6; ++j)
#pragma unroll
            for (int r = 0; r < 2; ++r) acc[j][r] = (f32x4){0.f, 0.f, 0.f, 0.f};

#pragma unroll
        for (int ks = 0; ks < K / 32; ++ks) {
            bf16x8 a0 = {}, a1 = {};
            int row0 = bm + r16;
            int row1 = bm + 16 + r16;
            if (row0 < n) a0 = *(const bf16x8*)(X + (size_t)row0 * K + ks * 32 + hi * 8);
            if (row1 < n) a1 = *(const bf16x8*)(X + (size_t)row1 * K + ks * 32 + hi * 8);
#pragma unroll
            for (int j = 0; j < 6; ++j) {
                int wl = j * 16 + r16;
                int kb = ks * 4 + hi;
                bf16x8 b = *(const bf16x8*)(smem + ((size_t)wl * UNITS + (kb ^ (wl & 7))) * 16);
                acc[j][0] = __builtin_amdgcn_mfma_f32_16x16x32_bf16(a0, b, acc[j][0], 0, 0, 0);
                acc[j][1] = __builtin_amdgcn_mfma_f32_16x16x32_bf16(a1, b, acc[j][1], 0, 0, 0);
            }
        }

#pragma unroll
        for (int j = 0; j < 6; ++j)
#pragma unroll
            for (int r = 0; r < 2; ++r)
#pragma unroll
                for (int q = 0; q < 4; ++q) {
                    int row = bm + r * 16 + hi * 4 + q;
                    if (row < n) C[(size_t)row * HC + p * 96 + j * 16 + r16] = acc[j][r][q];
                }
        __syncthreads();
    }
}

// ---------------- head GEMM (fp32): out[n,40] = B[n,192] @ Wo[40,192]^T + bo ----------------

template <int K, int M, bool ADD_BIAS>
__global__ __launch_bounds__(256) void gemm_xwt(const float* __restrict__ X,
                                                const float* __restrict__ W,
                                                const float* __restrict__ bias,
                                                float* __restrict__ C, int n) {
    const int BM = 128, BN = 64, BK = 16;
    __shared__ float Xs[BK][BM + 4];
    __shared__ float Ws[BK][BN + 4];
    int bm = blockIdx.x * BM;
    int bn = blockIdx.y * BN;
    int tid = threadIdx.x;
    int tx = tid & 15;
    int ty = tid >> 4;
    float acc[8][4] = {};

    for (int k0 = 0; k0 < K; k0 += BK) {
#pragma unroll
        for (int t = 0; t < 2; ++t) {
            int q = tid + t * 256;
            int row = q >> 2;
            int ks = (q & 3) * 4;
            int grow = bm + row;
            float4 v = make_float4(0.f, 0.f, 0.f, 0.f);
            if (grow < n) v = *(const float4*)(X + (size_t)grow * K + k0 + ks);
            Xs[ks + 0][row] = v.x; Xs[ks + 1][row] = v.y;
            Xs[ks + 2][row] = v.z; Xs[ks + 3][row] = v.w;
        }
        {
            int rowm = tid >> 2;
            int ks = (tid & 3) * 4;
            int gm = bn + rowm;
            float4 v = make_float4(0.f, 0.f, 0.f, 0.f);
            if (gm < M) v = *(const float4*)(W + (size_t)gm * K + k0 + ks);
            Ws[ks + 0][rowm] = v.x; Ws[ks + 1][rowm] = v.y;
            Ws[ks + 2][rowm] = v.z; Ws[ks + 3][rowm] = v.w;
        }
        __syncthreads();
#pragma unroll
        for (int kk = 0; kk < BK; ++kk) {
            float4 xa = *(const float4*)&Xs[kk][ty * 8];
            float4 xb = *(const float4*)&Xs[kk][ty * 8 + 4];
            float4 wa = *(const float4*)&Ws[kk][tx * 4];
            float xr[8] = {xa.x, xa.y, xa.z, xa.w, xb.x, xb.y, xb.z, xb.w};
            float wr[4] = {wa.x, wa.y, wa.z, wa.w};
#pragma unroll
            for (int i = 0; i < 8; ++i)
#pragma unroll
                for (int j = 0; j < 4; ++j) acc[i][j] += xr[i] * wr[j];
        }
        __syncthreads();
    }
#pragma unroll
    for (int i = 0; i < 8; ++i) {
        int grow = bm + ty * 8 + i;
        if (grow >= n) continue;
        int gcol = bn + tx * 4;
        if (gcol + 3 < M) {
            float4 v;
            v.x = acc[i][0]; v.y = acc[i][1]; v.z = acc[i][2]; v.w = acc[i][3];
            if (ADD_BIAS) {
                v.x += bias[gcol + 0]; v.y += bias[gcol + 1];
                v.z += bias[gcol + 2]; v.w += bias[gcol + 3];
            }
            *(float4*)(C + (size_t)grow * M + gcol) = v;
        } else {
#pragma unroll
            for (int j = 0; j < 4; ++j) {
                int gc = gcol + j;
                if (gc < M) {
                    float v = acc[i][j];
                    if (ADD_BIAS) v += bias[gc];
                    C[(size_t)grow * M + gc] = v;
                }
            }
        }
    }
}

// ---------------- prep: al/ar projections + bf16 feature copy ----------------

__global__ __launch_bounds__(256) void prep_kernel(const float* __restrict__ A,
                                                   const float* __restrict__ attl,
                                                   const float* __restrict__ attr,
                                                   float* __restrict__ al,
                                                   float* __restrict__ ar,
                                                   unsigned short* __restrict__ Abf,
                                                   int n) {
    int wave = threadIdx.x >> 6;
    int lane = threadIdx.x & 63;
    int node = blockIdx.x * 4 + wave;
    if (node >= n) return;
#pragma unroll
    for (int h = 0; h < NHEADS; ++h) {
        float v = A[(size_t)node * HC + h * HIDC + lane];
        Abf[(size_t)node * HC + h * HIDC + lane] = f2bf(v);
        float pl = v * attl[h * HIDC + lane];
        float pr = v * attr[h * HIDC + lane];
#pragma unroll
        for (int off = 32; off; off >>= 1) {
            pl += __shfl_xor(pl, off);
            pr += __shfl_xor(pr, off);
        }
        if (lane == 0) {
            al[node * NHEADS + h] = pl;
            ar[node * NHEADS + h] = pr;
        }
    }
}

// ---------------- edge softmax weights (normalized, fp32) ----------------

__global__ __launch_bounds__(256) void weight_kernel(const float* __restrict__ al,
                                                     const float* __restrict__ ar,
                                                     const int* __restrict__ rowp,
                                                     const int* __restrict__ esrc,
                                                     float* __restrict__ wgt, int n) {
    int node = blockIdx.x * 4 + (threadIdx.x >> 6);
    int lane = threadIdx.x & 63;
    if (node >= n) return;
    int e0 = rowp[node], e1 = rowp[node + 1];
    float ar0 = ar[node * 3 + 0], ar1 = ar[node * 3 + 1], ar2 = ar[node * 3 + 2];
    float m0 = -1e30f, m1 = -1e30f, m2 = -1e30f;
    for (int p = e0 + lane; p < e1; p += 64) {
        int s = esrc[p];
        m0 = fmaxf(m0, lrelu(al[s * 3 + 0] + ar0));
        m1 = fmaxf(m1, lrelu(al[s * 3 + 1] + ar1));
        m2 = fmaxf(m2, lrelu(al[s * 3 + 2] + ar2));
    }
#pragma unroll
    for (int off = 32; off; off >>= 1) {
        m0 = fmaxf(m0, __shfl_xor(m0, off));
        m1 = fmaxf(m1, __shfl_xor(m1, off));
        m2 = fmaxf(m2, __shfl_xor(m2, off));
    }
    float s0 = 0.f, s1 = 0.f, s2 = 0.f;
    for (int p = e0 + lane; p < e1; p += 64) {
        int s = esrc[p];
        s0 += __expf(lrelu(al[s * 3 + 0] + ar0) - m0);
        s1 += __expf(lrelu(al[s * 3 + 1] + ar1) - m1);
        s2 += __expf(lrelu(al[s * 3 + 2] + ar2) - m2);
    }
#pragma unroll
    for (int off = 32; off; off >>= 1) {
        s0 += __shfl_xor(s0, off);
        s1 += __shfl_xor(s1, off);
        s2 += __shfl_xor(s2, off);
    }
    float r0 = 1.f / (s0 + 1e-16f), r1 = 1.f / (s1 + 1e-16f), r2 = 1.f / (s2 + 1e-16f);
    for (int p = e0 + lane; p < e1; p += 64) {
        int s = esrc[p];
        wgt[p * 3 + 0] = __expf(lrelu(al[s * 3 + 0] + ar0) - m0) * r0;
        wgt[p * 3 + 1] = __expf(lrelu(al[s * 3 + 1] + ar1) - m1) * r1;
        wgt[p * 3 + 2] = __expf(lrelu(al[s * 3 + 2] + ar2) - m2) * r2;
    }
}

// ---------------- gather: wave per NODE, all 3 heads, lane-owned channels ----------------
// Lanes 0-47 each own 4 channels of the 192-ch row (head=lane>>4, c4=lane&15).
// No cross-lane reduction; esrc loaded once per edge (not 3x); per-node overhead 1x.
// 4-deep unroll keeps 4 x 384B rows in flight. Idle lanes clamped in-bounds.

template <bool RELU, bool OUT_BF16>
__global__ __launch_bounds__(256) void gather_kernel(const unsigned short* __restrict__ hfeat,
                                                     const float* __restrict__ wgt,
                                                     const int* __restrict__ rowp,
                                                     const int* __restrict__ esrc,
                                                     const float* __restrict__ bias,
                                                     void* __restrict__ outv, int n) {
    int node = blockIdx.x * 4 + (threadIdx.x >> 6);
    if (node >= n) return;
    int lane = threadIdx.x & 63;
    int head = lane >> 4;
    int headc = head > 2 ? 2 : head;          // keep idle lanes in-bounds
    int c4 = lane & 15;
    int e0 = rowp[node], e1 = rowp[node + 1];
    const unsigned short* base = hfeat + (size_t)headc * HIDC + c4 * 4;

    float4 acc = make_float4(0.f, 0.f, 0.f, 0.f);
    int e = e0;
    for (; e + 4 <= e1; e += 4) {
        int s0 = esrc[e + 0], s1 = esrc[e + 1], s2 = esrc[e + 2], s3 = esrc[e + 3];
        float w0 = wgt[(e + 0) * 3 + headc];
        float w1 = wgt[(e + 1) * 3 + headc];
        float w2 = wgt[(e + 2) * 3 + headc];
        float w3 = wgt[(e + 3) * 3 + headc];
        ushort4 u0 = *(const ushort4*)(base + (size_t)s0 * HC);
        ushort4 u1 = *(const ushort4*)(base + (size_t)s1 * HC);
        ushort4 u2 = *(const ushort4*)(base + (size_t)s2 * HC);
        ushort4 u3 = *(const ushort4*)(base + (size_t)s3 * HC);
        acc.x += w0 * bf2f(u0.x) + w1 * bf2f(u1.x) + w2 * bf2f(u2.x) + w3 * bf2f(u3.x);
        acc.y += w0 * bf2f(u0.y) + w1 * bf2f(u1.y) + w2 * bf2f(u2.y) + w3 * bf2f(u3.y);
        acc.z += w0 * bf2f(u0.z) + w1 * bf2f(u1.z) + w2 * bf2f(u2.z) + w3 * bf2f(u3.z);
        acc.w += w0 * bf2f(u0.w) + w1 * bf2f(u1.w) + w2 * bf2f(u2.w) + w3 * bf2f(u3.w);
    }
    for (; e < e1; ++e) {
        int s0 = esrc[e];
        float w0 = wgt[e * 3 + headc];
        ushort4 u0 = *(const ushort4*)(base + (size_t)s0 * HC);
        acc.x += w0 * bf2f(u0.x);
        acc.y += w0 * bf2f(u0.y);
        acc.z += w0 * bf2f(u0.z);
        acc.w += w0 * bf2f(u0.w);
    }
    if (lane < 48) {
        const float4 bv = *(const float4*)(bias + lane * 4);
        float4 v;
        v.x = acc.x + bv.x; v.y = acc.y + bv.y;
        v.z = acc.z + bv.z; v.w = acc.w + bv.w;
        if (RELU) {
            v.x = fmaxf(v.x, 0.f); v.y = fmaxf(v.y, 0.f);
            v.z = fmaxf(v.z, 0.f); v.w = fmaxf(v.w, 0.f);
        }
        size_t idx = (size_t)node * HC + lane * 4;
        if (OUT_BF16) {
            ushort4 u;
            u.x = f2bf(v.x); u.y = f2bf(v.y); u.z = f2bf(v.z); u.w = f2bf(v.w);
            *(ushort4*)((unsigned short*)outv + idx) = u;
        } else {
            *(float4*)((float*)outv + idx) = v;
        }
    }
}

// ---------------- launch ----------------

extern "C" void kernel_launch(void* const* d_in, const int* in_sizes, int n_in,
                              void* d_out, int out_size, void* d_ws, size_t ws_size,
                              hipStream_t stream) {
    const float* x     = (const float*)d_in[0];
    const int*   ei    = (const int*)d_in[1];
    const float* W1    = (const float*)d_in[2];
    const float* attl1 = (const float*)d_in[3];
    const float* attr1 = (const float*)d_in[4];
    const float* b1    = (const float*)d_in[5];
    const float* W2    = (const float*)d_in[6];
    const float* attl2 = (const float*)d_in[7];
    const float* attr2 = (const float*)d_in[8];
    const float* b2    = (const float*)d_in[9];
    const float* Wo    = (const float*)d_in[10];
    const float* bo    = (const float*)d_in[11];
    float* outp = (float*)d_out;

    const int n = NNODES;
    const int E_ = NEDGES;
    const int ET = E_ + n;

    char* ws = (char*)d_ws;
    size_t off = 0;
    auto take = [&](size_t bytes) {
        size_t p = off;
        off += (bytes + 255) & ~(size_t)255;
        return p;
    };
    float* A            = (float*)(ws + take((size_t)n * HC * 4));
    unsigned short* Abf = (unsigned short*)(ws + take((size_t)n * HC * 2));
    unsigned short* Bbf = (unsigned short*)(ws + take((size_t)n * HC * 2));
    unsigned short* xbf = (unsigned short*)(ws + take((size_t)n * 128 * 2));
    unsigned short* W1bf = (unsigned short*)(ws + take((size_t)HC * 128 * 2));
    unsigned short* W2bf = (unsigned short*)(ws + take((size_t)HC * HC * 2));
    float* al   = (float*)(ws + take((size_t)n * 3 * 4));
    float* ar   = (float*)(ws + take((size_t)n * 3 * 4));
    int* rowp   = (int*)(ws + take((size_t)(n + 1) * 4));
    int* deg    = (int*)(ws + take((size_t)n * 4));
    int* cursor = (int*)(ws + take((size_t)n * 4));
    int* esrc   = (int*)(ws + take((size_t)ET * 4));
    int* bsum   = (int*)(ws + take((size_t)SB * 4));
    int* boff   = (int*)(ws + take((size_t)SB * 4));
    (void)ws_size;
    float* wgt = (float*)d_out;  // overwritten by head GEMM afterwards

    hipMemsetAsync(deg, 0, (size_t)n * 4, stream);
    hipMemsetAsync(cursor, 0, (size_t)n * 4, stream);

    int xc4 = n * 128 / 4;
    cast_bf16_kernel<<<2048, 256, 0, stream>>>(x, xbf, xc4);
    cast_bf16_kernel<<<(HC * 128 / 4 + 255) / 256, 256, 0, stream>>>(W1, W1bf, HC * 128 / 4);
    cast_bf16_kernel<<<(HC * HC / 4 + 255) / 256, 256, 0, stream>>>(W2, W2bf, HC * HC / 4);

    int eb = 256;
    int eg = (ET + eb - 1) / eb;
    hist_kernel<<<eg, eb, 0, stream>>>(ei, deg, E_, n);
    bsum_kernel<<<SB, 256, 0, stream>>>(deg, bsum, n);
    bscan_kernel<<<1, SB, 0, stream>>>(bsum, boff, rowp, n);
    scan_chunk_kernel<<<SB, 256, 0, stream>>>(deg, boff, rowp, n);
    scatter_kernel<<<eg, eb, 0, stream>>>(ei, rowp, cursor, esrc, E_, n);

    int mfma_grid = (n + 95) / 96;
    dim3 go((n + 127) / 128, 1);
    int nodeg4 = (n + 3) / 4;

    // layer 1
    gemm_mfma<128><<<mfma_grid, 192, 0, stream>>>(xbf, W1bf, A, n);
    prep_kernel<<<nodeg4, 256, 0, stream>>>(A, attl1, attr1, al, ar, Abf, n);
    weight_kernel<<<nodeg4, 256, 0, stream>>>(al, ar, rowp, esrc, wgt, n);
    gather_kernel<true, true><<<nodeg4, 256, 0, stream>>>(Abf, wgt, rowp, esrc, b1, Bbf, n);
    // layer 2
    gemm_mfma<192><<<mfma_grid, 192, 0, stream>>>(Bbf, W2bf, A, n);
    prep_kernel<<<nodeg4, 256, 0, stream>>>(A, attl2, attr2, al, ar, Abf, n);
    weight_kernel<<<nodeg4, 256, 0, stream>>>(al, ar, rowp, esrc, wgt, n);
    gather_kernel<true, false><<<nodeg4, 256, 0, stream>>>(Abf, wgt, rowp, esrc, b2, A, n);
    // output head (fp32)
    gemm_xwt<HC, NCLS, true><<<go, 256, 0, stream>>>(A, Wo, bo, outp, n);
}

// Round 9
// 258.423 us; speedup vs baseline: 3.6095x; 1.1276x over previous
//
#include <hip/hip_runtime.h>
#include <hip/hip_bf16.h>

// GAT 2-layer + linear head.
// Layer GEMMs: bf16 MFMA (fp32 accum, fp32 in-flight cvt), epilogue fuses
// al/ar projection + bf16 feature write. Gather fuses softmax-weight compute.
// N=50000, E=400000 (+N self loops), IN_DIM=128, HEADS=3, HID=64 (HC=192), CLASSES=40.

#define NNODES 50000
#define NEDGES 400000
#define HC 192
#define NHEADS 3
#define HIDC 64
#define NCLS 40

#define SB 256
#define CHUNK 196

typedef __attribute__((ext_vector_type(8))) short bf16x8;
typedef __attribute__((ext_vector_type(4))) float f32x4;

__device__ __forceinline__ float lrelu(float a) { return a > 0.f ? a : 0.2f * a; }
__device__ __forceinline__ float bf2f(unsigned short u) {
    return __uint_as_float((unsigned)u << 16);
}
__device__ __forceinline__ unsigned short f2bf(float f) {
    __hip_bfloat16 b = __float2bfloat16(f);
    return *(unsigned short*)&b;
}

// ---------------- CSR build ----------------

__global__ void hist_kernel(const int* __restrict__ ei, int* __restrict__ deg,
                            int E_, int n) {
    int e = blockIdx.x * blockDim.x + threadIdx.x;
    int ET = E_ + n;
    if (e >= ET) return;
    int d = (e < E_) ? ei[E_ + e] : (e - E_);
    atomicAdd(&deg[d], 1);
}

__global__ __launch_bounds__(256) void bsum_kernel(const int* __restrict__ deg,
                                                   int* __restrict__ bsum, int n) {
    int b = blockIdx.x, t = threadIdx.x;
    int i = b * CHUNK + t;
    int v = (t < CHUNK && i < n) ? deg[i] : 0;
#pragma unroll
    for (int off = 32; off; off >>= 1) v += __shfl_xor(v, off);
    __shared__ int sh[4];
    if ((t & 63) == 0) sh[t >> 6] = v;
    __syncthreads();
    if (t == 0) bsum[b] = sh[0] + sh[1] + sh[2] + sh[3];
}

__global__ __launch_bounds__(256) void bscan_kernel(const int* __restrict__ bsum,
                                                    int* __restrict__ boff,
                                                    int* __restrict__ rowp, int n) {
    __shared__ int sh[SB];
    int t = threadIdx.x;
    int v = bsum[t];
    sh[t] = v;
    __syncthreads();
    for (int off = 1; off < SB; off <<= 1) {
        int u = (t >= off) ? sh[t - off] : 0;
        __syncthreads();
        sh[t] += u;
        __syncthreads();
    }
    boff[t] = sh[t] - v;
    if (t == SB - 1) rowp[n] = sh[t];
}

__global__ __launch_bounds__(256) void scan_chunk_kernel(const int* __restrict__ deg,
                                                         const int* __restrict__ boff,
                                                         int* __restrict__ rowp, int n) {
    __shared__ int sh[256];
    int b = blockIdx.x, t = threadIdx.x;
    int i = b * CHUNK + t;
    int v = (t < CHUNK && i < n) ? deg[i] : 0;
    sh[t] = v;
    __syncthreads();
    for (int off = 1; off < 256; off <<= 1) {
        int u = (t >= off) ? sh[t - off] : 0;
        __syncthreads();
        sh[t] += u;
        __syncthreads();
    }
    if (t < CHUNK && i < n) rowp[i] = boff[b] + sh[t] - v;
}

__global__ void scatter_kernel(const int* __restrict__ ei, const int* __restrict__ rowp,
                               int* __restrict__ cursor, int* __restrict__ esrc,
                               int E_, int n) {
    int e = blockIdx.x * blockDim.x + threadIdx.x;
    int ET = E_ + n;
    if (e >= ET) return;
    int s, d;
    if (e < E_) { s = ei[e]; d = ei[E_ + e]; }
    else        { s = e - E_; d = s; }
    int pos = atomicAdd(&cursor[d], 1);
    esrc[rowp[d] + pos] = s;
}

// ---------------- MFMA GEMM + fused epilogue ----------------
// C[n,192] = X[n,K] @ W[192,K]^T; X fp32 (XF32) or bf16; W fp32 (cvt at stage).
// Epilogue: writes Cbf (bf16) and per-head al/ar projections (from fp32 acc).
// 192 threads = 3 waves; wave = 32 rows x 96-col panel; 2 panels sequential.
// mfma_f32_16x16x32_bf16: C col=lane&15, row=(lane>>4)*4+reg [m89].

template <int K, bool XF32>
__global__ __launch_bounds__(192) void gemm_mfma(const void* __restrict__ Xv,
                                                 const float* __restrict__ Wf,
                                                 const float* __restrict__ attl,
                                                 const float* __restrict__ attr,
                                                 unsigned short* __restrict__ Cbf,
                                                 float* __restrict__ al,
                                                 float* __restrict__ ar, int n) {
    constexpr int UNITS = K / 8;          // 16B bf16 units per W row
    __shared__ char smem[96 * K * 2];     // one 96-row W panel, swizzled
    int tid = threadIdx.x;
    int wave = tid >> 6, lane = tid & 63;
    int r16 = lane & 15;
    int hi = lane >> 4;
    int bm = blockIdx.x * 96 + wave * 32;

    float alp[3][2][4] = {};
    float arp[3][2][4] = {};

#pragma unroll
    for (int p = 0; p < 2; ++p) {
        // stage W rows [p*96, +96) into LDS: fp32 -> bf16, swizzled
        for (int u = tid; u < 96 * UNITS; u += 192) {
            int row = u / UNITS, kb = u % UNITS;
            const float* src = Wf + (size_t)(p * 96 + row) * K + kb * 8;
            float4 va = *(const float4*)src;
            float4 vb = *(const float4*)(src + 4);
            bf16x8 b;
            unsigned short* bp = (unsigned short*)&b;
            bp[0] = f2bf(va.x); bp[1] = f2bf(va.y); bp[2] = f2bf(va.z); bp[3] = f2bf(va.w);
            bp[4] = f2bf(vb.x); bp[5] = f2bf(vb.y); bp[6] = f2bf(vb.z); bp[7] = f2bf(vb.w);
            *(bf16x8*)(smem + ((size_t)row * UNITS + (kb ^ (row & 7))) * 16) = b;
        }
        __syncthreads();

        f32x4 acc[6][2];
#pragma unroll
        for (int j = 0; j < 6; ++j)
#pragma unroll
            for (int r = 0; r < 2; ++r) acc[j][r] = (f32x4){0.f, 0.f, 0.f, 0.f};

#pragma unroll
        for (int ks = 0; ks < K / 32; ++ks) {
            bf16x8 a0 = {}, a1 = {};
            int row0 = bm + r16;
            int row1 = bm + 16 + r16;
            if (XF32) {
                const float* Xf = (const float*)Xv;
                if (row0 < n) {
                    const float* s0 = Xf + (size_t)row0 * K + ks * 32 + hi * 8;
                    float4 va = *(const float4*)s0, vb = *(const float4*)(s0 + 4);
                    unsigned short* ap = (unsigned short*)&a0;
                    ap[0] = f2bf(va.x); ap[1] = f2bf(va.y); ap[2] = f2bf(va.z); ap[3] = f2bf(va.w);
                    ap[4] = f2bf(vb.x); ap[5] = f2bf(vb.y); ap[6] = f2bf(vb.z); ap[7] = f2bf(vb.w);
                }
                if (row1 < n) {
                    const float* s1 = Xf + (size_t)row1 * K + ks * 32 + hi * 8;
                    float4 va = *(const float4*)s1, vb = *(const float4*)(s1 + 4);
                    unsigned short* ap = (unsigned short*)&a1;
                    ap[0] = f2bf(va.x); ap[1] = f2bf(va.y); ap[2] = f2bf(va.z); ap[3] = f2bf(va.w);
                    ap[4] = f2bf(vb.x); ap[5] = f2bf(vb.y); ap[6] = f2bf(vb.z); ap[7] = f2bf(vb.w);
                }
            } else {
                const unsigned short* Xb = (const unsigned short*)Xv;
                if (row0 < n) a0 = *(const bf16x8*)(Xb + (size_t)row0 * K + ks * 32 + hi * 8);
                if (row1 < n) a1 = *(const bf16x8*)(Xb + (size_t)row1 * K + ks * 32 + hi * 8);
            }
#pragma unroll
            for (int j = 0; j < 6; ++j) {
                int wl = j * 16 + r16;
                int kb = ks * 4 + hi;
                bf16x8 b = *(const bf16x8*)(smem + ((size_t)wl * UNITS + (kb ^ (wl & 7))) * 16);
                acc[j][0] = __builtin_amdgcn_mfma_f32_16x16x32_bf16(a0, b, acc[j][0], 0, 0, 0);
                acc[j][1] = __builtin_amdgcn_mfma_f32_16x16x32_bf16(a1, b, acc[j][1], 0, 0, 0);
            }
        }

        // epilogue for this panel: al/ar partials (head = f(p,j), compile-time)
        float atl[6], atr[6];
#pragma unroll
        for (int j = 0; j < 6; ++j) {
            int col = p * 96 + j * 16 + r16;
            atl[j] = attl[col];
            atr[j] = attr[col];
        }
#pragma unroll
        for (int j = 0; j < 6; ++j) {
            const int hj = (p * 96 + j * 16) >> 6;   // constant-folded
#pragma unroll
            for (int r = 0; r < 2; ++r)
#pragma unroll
                for (int q = 0; q < 4; ++q) {
                    alp[hj][r][q] += acc[j][r][q] * atl[j];
                    arp[hj][r][q] += acc[j][r][q] * atr[j];
                }
        }
        // bf16 feature write
#pragma unroll
        for (int j = 0; j < 6; ++j)
#pragma unroll
            for (int r = 0; r < 2; ++r)
#pragma unroll
                for (int q = 0; q < 4; ++q) {
                    int row = bm + r * 16 + hi * 4 + q;
                    if (row < n)
                        Cbf[(size_t)row * HC + p * 96 + j * 16 + r16] = f2bf(acc[j][r][q]);
                }
        __syncthreads();
    }

    // reduce al/ar partials over the 16-lane r16 group and store
#pragma unroll
    for (int h = 0; h < 3; ++h)
#pragma unroll
        for (int r = 0; r < 2; ++r)
#pragma unroll
            for (int q = 0; q < 4; ++q) {
#pragma unroll
                for (int off = 1; off < 16; off <<= 1) {
                    alp[h][r][q] += __shfl_xor(alp[h][r][q], off);
                    arp[h][r][q] += __shfl_xor(arp[h][r][q], off);
                }
            }
    if (r16 == 0) {
#pragma unroll
        for (int r = 0; r < 2; ++r)
#pragma unroll
            for (int q = 0; q < 4; ++q) {
                int row = bm + r * 16 + hi * 4 + q;
                if (row < n) {
#pragma unroll
                    for (int h = 0; h < 3; ++h) {
                        al[row * 3 + h] = alp[h][r][q];
                        ar[row * 3 + h] = arp[h][r][q];
                    }
                }
            }
    }
}

// ---------------- head GEMM (fp32): out[n,40] = B[n,192] @ Wo[40,192]^T + bo ----------------

template <int K, int M, bool ADD_BIAS>
__global__ __launch_bounds__(256) void gemm_xwt(const float* __restrict__ X,
                                                const float* __restrict__ W,
                                                const float* __restrict__ bias,
                                                float* __restrict__ C, int n) {
    const int BM = 128, BN = 64, BK = 16;
    __shared__ float Xs[BK][BM + 4];
    __shared__ float Ws[BK][BN + 4];
    int bm = blockIdx.x * BM;
    int bn = blockIdx.y * BN;
    int tid = threadIdx.x;
    int tx = tid & 15;
    int ty = tid >> 4;
    float acc[8][4] = {};

    for (int k0 = 0; k0 < K; k0 += BK) {
#pragma unroll
        for (int t = 0; t < 2; ++t) {
            int q = tid + t * 256;
            int row = q >> 2;
            int ks = (q & 3) * 4;
            int grow = bm + row;
            float4 v = make_float4(0.f, 0.f, 0.f, 0.f);
            if (grow < n) v = *(const float4*)(X + (size_t)grow * K + k0 + ks);
            Xs[ks + 0][row] = v.x; Xs[ks + 1][row] = v.y;
            Xs[ks + 2][row] = v.z; Xs[ks + 3][row] = v.w;
        }
        {
            int rowm = tid >> 2;
            int ks = (tid & 3) * 4;
            int gm = bn + rowm;
            float4 v = make_float4(0.f, 0.f, 0.f, 0.f);
            if (gm < M) v = *(const float4*)(W + (size_t)gm * K + k0 + ks);
            Ws[ks + 0][rowm] = v.x; Ws[ks + 1][rowm] = v.y;
            Ws[ks + 2][rowm] = v.z; Ws[ks + 3][rowm] = v.w;
        }
        __syncthreads();
#pragma unroll
        for (int kk = 0; kk < BK; ++kk) {
            float4 xa = *(const float4*)&Xs[kk][ty * 8];
            float4 xb = *(const float4*)&Xs[kk][ty * 8 + 4];
            float4 wa = *(const float4*)&Ws[kk][tx * 4];
            float xr[8] = {xa.x, xa.y, xa.z, xa.w, xb.x, xb.y, xb.z, xb.w};
            float wr[4] = {wa.x, wa.y, wa.z, wa.w};
#pragma unroll
            for (int i = 0; i < 8; ++i)
#pragma unroll
                for (int j = 0; j < 4; ++j) acc[i][j] += xr[i] * wr[j];
        }
        __syncthreads();
    }
#pragma unroll
    for (int i = 0; i < 8; ++i) {
        int grow = bm + ty * 8 + i;
        if (grow >= n) continue;
        int gcol = bn + tx * 4;
        if (gcol + 3 < M) {
            float4 v;
            v.x = acc[i][0]; v.y = acc[i][1]; v.z = acc[i][2]; v.w = acc[i][3];
            if (ADD_BIAS) {
                v.x += bias[gcol + 0]; v.y += bias[gcol + 1];
                v.z += bias[gcol + 2]; v.w += bias[gcol + 3];
            }
            *(float4*)(C + (size_t)grow * M + gcol) = v;
        } else {
#pragma unroll
            for (int j = 0; j < 4; ++j) {
                int gc = gcol + j;
                if (gc < M) {
                    float v = acc[i][j];
                    if (ADD_BIAS) v += bias[gc];
                    C[(size_t)grow * M + gc] = v;
                }
            }
        }
    }
}

// ---------------- fused softmax-weight + gather: wave per node ----------------
// Phases 1-2 (all 64 lanes, strided over edges): per-head max, then exp-sum.
// Phase 3: lanes 0-47 own channels (head=lane>>4, c4=lane&15); per edge the
// weight is recomputed inline (al load broadcasts within 16-lane groups).

template <bool RELU, bool OUT_BF16>
__global__ __launch_bounds__(256) void gatherw_kernel(const unsigned short* __restrict__ hfeat,
                                                      const float* __restrict__ al,
                                                      const float* __restrict__ ar,
                                                      const int* __restrict__ rowp,
                                                      const int* __restrict__ esrc,
                                                      const float* __restrict__ bias,
                                                      void* __restrict__ outv, int n) {
    int node = blockIdx.x * 4 + (threadIdx.x >> 6);
    if (node >= n) return;
    int lane = threadIdx.x & 63;
    int e0 = rowp[node], e1 = rowp[node + 1];
    float ar0 = ar[node * 3 + 0], ar1 = ar[node * 3 + 1], ar2 = ar[node * 3 + 2];

    // pass 1: per-head max
    float m0 = -1e30f, m1 = -1e30f, m2 = -1e30f;
    for (int p = e0 + lane; p < e1; p += 64) {
        int s = esrc[p];
        m0 = fmaxf(m0, lrelu(al[s * 3 + 0] + ar0));
        m1 = fmaxf(m1, lrelu(al[s * 3 + 1] + ar1));
        m2 = fmaxf(m2, lrelu(al[s * 3 + 2] + ar2));
    }
#pragma unroll
    for (int off = 32; off; off >>= 1) {
        m0 = fmaxf(m0, __shfl_xor(m0, off));
        m1 = fmaxf(m1, __shfl_xor(m1, off));
        m2 = fmaxf(m2, __shfl_xor(m2, off));
    }
    // pass 2: denom
    float s0 = 0.f, s1 = 0.f, s2 = 0.f;
    for (int p = e0 + lane; p < e1; p += 64) {
        int s = esrc[p];
        s0 += __expf(lrelu(al[s * 3 + 0] + ar0) - m0);
        s1 += __expf(lrelu(al[s * 3 + 1] + ar1) - m1);
        s2 += __expf(lrelu(al[s * 3 + 2] + ar2) - m2);
    }
#pragma unroll
    for (int off = 32; off; off >>= 1) {
        s0 += __shfl_xor(s0, off);
        s1 += __shfl_xor(s1, off);
        s2 += __shfl_xor(s2, off);
    }
    float r0 = 1.f / (s0 + 1e-16f), r1 = 1.f / (s1 + 1e-16f), r2 = 1.f / (s2 + 1e-16f);

    // per-lane head parameters
    int head = lane >> 4;
    int headc = head > 2 ? 2 : head;
    float mh  = headc == 0 ? m0 : (headc == 1 ? m1 : m2);
    float rh  = headc == 0 ? r0 : (headc == 1 ? r1 : r2);
    float arh = headc == 0 ? ar0 : (headc == 1 ? ar1 : ar2);
    int c4 = lane & 15;
    const unsigned short* base = hfeat + (size_t)headc * HIDC + c4 * 4;

    float4 acc = make_float4(0.f, 0.f, 0.f, 0.f);
    int e = e0;
    for (; e + 4 <= e1; e += 4) {
        int s0i = esrc[e + 0], s1i = esrc[e + 1], s2i = esrc[e + 2], s3i = esrc[e + 3];
        float w0 = __expf(lrelu(al[s0i * 3 + headc] + arh) - mh) * rh;
        float w1 = __expf(lrelu(al[s1i * 3 + headc] + arh) - mh) * rh;
        float w2 = __expf(lrelu(al[s2i * 3 + headc] + arh) - mh) * rh;
        float w3 = __expf(lrelu(al[s3i * 3 + headc] + arh) - mh) * rh;
        ushort4 u0 = *(const ushort4*)(base + (size_t)s0i * HC);
        ushort4 u1 = *(const ushort4*)(base + (size_t)s1i * HC);
        ushort4 u2 = *(const ushort4*)(base + (size_t)s2i * HC);
        ushort4 u3 = *(const ushort4*)(base + (size_t)s3i * HC);
        acc.x += w0 * bf2f(u0.x) + w1 * bf2f(u1.x) + w2 * bf2f(u2.x) + w3 * bf2f(u3.x);
        acc.y += w0 * bf2f(u0.y) + w1 * bf2f(u1.y) + w2 * bf2f(u2.y) + w3 * bf2f(u3.y);
        acc.z += w0 * bf2f(u0.z) + w1 * bf2f(u1.z) + w2 * bf2f(u2.z) + w3 * bf2f(u3.z);
        acc.w += w0 * bf2f(u0.w) + w1 * bf2f(u1.w) + w2 * bf2f(u2.w) + w3 * bf2f(u3.w);
    }
    for (; e < e1; ++e) {
        int si = esrc[e];
        float w = __expf(lrelu(al[si * 3 + headc] + arh) - mh) * rh;
        ushort4 u = *(const ushort4*)(base + (size_t)si * HC);
        acc.x += w * bf2f(u.x);
        acc.y += w * bf2f(u.y);
        acc.z += w * bf2f(u.z);
        acc.w += w * bf2f(u.w);
    }
    if (lane < 48) {
        const float4 bv = *(const float4*)(bias + lane * 4);
        float4 v;
        v.x = acc.x + bv.x; v.y = acc.y + bv.y;
        v.z = acc.z + bv.z; v.w = acc.w + bv.w;
        if (RELU) {
            v.x = fmaxf(v.x, 0.f); v.y = fmaxf(v.y, 0.f);
            v.z = fmaxf(v.z, 0.f); v.w = fmaxf(v.w, 0.f);
        }
        size_t idx = (size_t)node * HC + lane * 4;
        if (OUT_BF16) {
            ushort4 u;
            u.x = f2bf(v.x); u.y = f2bf(v.y); u.z = f2bf(v.z); u.w = f2bf(v.w);
            *(ushort4*)((unsigned short*)outv + idx) = u;
        } else {
            *(float4*)((float*)outv + idx) = v;
        }
    }
}

// ---------------- launch ----------------

extern "C" void kernel_launch(void* const* d_in, const int* in_sizes, int n_in,
                              void* d_out, int out_size, void* d_ws, size_t ws_size,
                              hipStream_t stream) {
    const float* x     = (const float*)d_in[0];
    const int*   ei    = (const int*)d_in[1];
    const float* W1    = (const float*)d_in[2];
    const float* attl1 = (const float*)d_in[3];
    const float* attr1 = (const float*)d_in[4];
    const float* b1    = (const float*)d_in[5];
    const float* W2    = (const float*)d_in[6];
    const float* attl2 = (const float*)d_in[7];
    const float* attr2 = (const float*)d_in[8];
    const float* b2    = (const float*)d_in[9];
    const float* Wo    = (const float*)d_in[10];
    const float* bo    = (const float*)d_in[11];
    float* outp = (float*)d_out;

    const int n = NNODES;
    const int E_ = NEDGES;
    const int ET = E_ + n;

    char* ws = (char*)d_ws;
    size_t off = 0;
    auto take = [&](size_t bytes) {
        size_t p = off;
        off += (bytes + 255) & ~(size_t)255;
        return p;
    };
    float* A            = (float*)(ws + take((size_t)n * HC * 4));          // gather2 fp32 out
    unsigned short* Abf = (unsigned short*)(ws + take((size_t)n * HC * 2)); // gemm bf16 feats
    unsigned short* Bbf = (unsigned short*)(ws + take((size_t)n * HC * 2)); // gather1 bf16 out
    float* al   = (float*)(ws + take((size_t)n * 3 * 4));
    float* ar   = (float*)(ws + take((size_t)n * 3 * 4));
    int* rowp   = (int*)(ws + take((size_t)(n + 1) * 4));
    int* deg    = (int*)(ws + take((size_t)n * 4));
    int* cursor = (int*)(ws + take((size_t)n * 4));
    int* esrc   = (int*)(ws + take((size_t)ET * 4));
    int* bsum   = (int*)(ws + take((size_t)SB * 4));
    int* boff   = (int*)(ws + take((size_t)SB * 4));
    (void)ws_size;

    hipMemsetAsync(deg, 0, (size_t)n * 4, stream);
    hipMemsetAsync(cursor, 0, (size_t)n * 4, stream);

    int eb = 256;
    int eg = (ET + eb - 1) / eb;
    hist_kernel<<<eg, eb, 0, stream>>>(ei, deg, E_, n);
    bsum_kernel<<<SB, 256, 0, stream>>>(deg, bsum, n);
    bscan_kernel<<<1, SB, 0, stream>>>(bsum, boff, rowp, n);
    scan_chunk_kernel<<<SB, 256, 0, stream>>>(deg, boff, rowp, n);
    scatter_kernel<<<eg, eb, 0, stream>>>(ei, rowp, cursor, esrc, E_, n);

    int mfma_grid = (n + 95) / 96;
    dim3 go((n + 127) / 128, 1);
    int nodeg4 = (n + 3) / 4;

    // layer 1: gemm (fp32 x in, bf16 feats + al/ar out) -> fused gather
    gemm_mfma<128, true><<<mfma_grid, 192, 0, stream>>>(x, W1, attl1, attr1, Abf, al, ar, n);
    gatherw_kernel<true, true><<<nodeg4, 256, 0, stream>>>(Abf, al, ar, rowp, esrc, b1, Bbf, n);
    // layer 2: gemm (bf16 in) -> fused gather (fp32 out for head)
    gemm_mfma<192, false><<<mfma_grid, 192, 0, stream>>>(Bbf, W2, attl2, attr2, Abf, al, ar, n);
    gatherw_kernel<true, false><<<nodeg4, 256, 0, stream>>>(Abf, al, ar, rowp, esrc, b2, A, n);
    // output head (fp32)
    gemm_xwt<HC, NCLS, true><<<go, 256, 0, stream>>>(A, Wo, bo, outp, n);
}

// Round 10
// 233.910 us; speedup vs baseline: 3.9877x; 1.1048x over previous
//
#include <hip/hip_runtime.h>
#include <hip/hip_bf16.h>

// GAT 2-layer + linear head.
// Layer GEMMs: bf16 MFMA (fp32 accum, in-flight cvt), epilogue fuses al/ar
// projection + bf16 feature write. Gather: single-pass unnormalized softmax
// (no max-subtract: |alpha| <= ~5 << 88, fp32-exp-safe; exact identity).
// N=50000, E=400000 (+N self loops), IN_DIM=128, HEADS=3, HID=64 (HC=192), CLASSES=40.

#define NNODES 50000
#define NEDGES 400000
#define HC 192
#define NHEADS 3
#define HIDC 64
#define NCLS 40

#define SB 256
#define CHUNK 196

typedef __attribute__((ext_vector_type(8))) short bf16x8;
typedef __attribute__((ext_vector_type(4))) float f32x4;

__device__ __forceinline__ float lrelu(float a) { return a > 0.f ? a : 0.2f * a; }
__device__ __forceinline__ float bf2f(unsigned short u) {
    return __uint_as_float((unsigned)u << 16);
}
__device__ __forceinline__ unsigned short f2bf(float f) {
    __hip_bfloat16 b = __float2bfloat16(f);
    return *(unsigned short*)&b;
}

// ---------------- CSR build ----------------

__global__ void hist_kernel(const int* __restrict__ ei, int* __restrict__ deg,
                            int E_, int n) {
    int e = blockIdx.x * blockDim.x + threadIdx.x;
    int ET = E_ + n;
    if (e >= ET) return;
    int d = (e < E_) ? ei[E_ + e] : (e - E_);
    atomicAdd(&deg[d], 1);
}

__global__ __launch_bounds__(256) void bsum_kernel(const int* __restrict__ deg,
                                                   int* __restrict__ bsum, int n) {
    int b = blockIdx.x, t = threadIdx.x;
    int i = b * CHUNK + t;
    int v = (t < CHUNK && i < n) ? deg[i] : 0;
#pragma unroll
    for (int off = 32; off; off >>= 1) v += __shfl_xor(v, off);
    __shared__ int sh[4];
    if ((t & 63) == 0) sh[t >> 6] = v;
    __syncthreads();
    if (t == 0) bsum[b] = sh[0] + sh[1] + sh[2] + sh[3];
}

__global__ __launch_bounds__(256) void bscan_kernel(const int* __restrict__ bsum,
                                                    int* __restrict__ boff,
                                                    int* __restrict__ rowp, int n) {
    __shared__ int sh[SB];
    int t = threadIdx.x;
    int v = bsum[t];
    sh[t] = v;
    __syncthreads();
    for (int off = 1; off < SB; off <<= 1) {
        int u = (t >= off) ? sh[t - off] : 0;
        __syncthreads();
        sh[t] += u;
        __syncthreads();
    }
    boff[t] = sh[t] - v;
    if (t == SB - 1) rowp[n] = sh[t];
}

__global__ __launch_bounds__(256) void scan_chunk_kernel(const int* __restrict__ deg,
                                                         const int* __restrict__ boff,
                                                         int* __restrict__ rowp, int n) {
    __shared__ int sh[256];
    int b = blockIdx.x, t = threadIdx.x;
    int i = b * CHUNK + t;
    int v = (t < CHUNK && i < n) ? deg[i] : 0;
    sh[t] = v;
    __syncthreads();
    for (int off = 1; off < 256; off <<= 1) {
        int u = (t >= off) ? sh[t - off] : 0;
        __syncthreads();
        sh[t] += u;
        __syncthreads();
    }
    if (t < CHUNK && i < n) rowp[i] = boff[b] + sh[t] - v;
}

__global__ void scatter_kernel(const int* __restrict__ ei, const int* __restrict__ rowp,
                               int* __restrict__ cursor, int* __restrict__ esrc,
                               int E_, int n) {
    int e = blockIdx.x * blockDim.x + threadIdx.x;
    int ET = E_ + n;
    if (e >= ET) return;
    int s, d;
    if (e < E_) { s = ei[e]; d = ei[E_ + e]; }
    else        { s = e - E_; d = s; }
    int pos = atomicAdd(&cursor[d], 1);
    esrc[rowp[d] + pos] = s;
}

// ---------------- MFMA GEMM + fused epilogue ----------------
// C[n,192] = X[n,K] @ W[192,K]^T; X fp32 (XF32) or bf16; W fp32 (cvt at stage).
// Epilogue: writes Cbf (bf16) and per-head al/ar projections (from fp32 acc).

template <int K, bool XF32>
__global__ __launch_bounds__(192) void gemm_mfma(const void* __restrict__ Xv,
                                                 const float* __restrict__ Wf,
                                                 const float* __restrict__ attl,
                                                 const float* __restrict__ attr,
                                                 unsigned short* __restrict__ Cbf,
                                                 float* __restrict__ al,
                                                 float* __restrict__ ar, int n) {
    constexpr int UNITS = K / 8;
    __shared__ char smem[96 * K * 2];
    int tid = threadIdx.x;
    int wave = tid >> 6, lane = tid & 63;
    int r16 = lane & 15;
    int hi = lane >> 4;
    int bm = blockIdx.x * 96 + wave * 32;

    float alp[3][2][4] = {};
    float arp[3][2][4] = {};

#pragma unroll
    for (int p = 0; p < 2; ++p) {
        for (int u = tid; u < 96 * UNITS; u += 192) {
            int row = u / UNITS, kb = u % UNITS;
            const float* src = Wf + (size_t)(p * 96 + row) * K + kb * 8;
            float4 va = *(const float4*)src;
            float4 vb = *(const float4*)(src + 4);
            bf16x8 b;
            unsigned short* bp = (unsigned short*)&b;
            bp[0] = f2bf(va.x); bp[1] = f2bf(va.y); bp[2] = f2bf(va.z); bp[3] = f2bf(va.w);
            bp[4] = f2bf(vb.x); bp[5] = f2bf(vb.y); bp[6] = f2bf(vb.z); bp[7] = f2bf(vb.w);
            *(bf16x8*)(smem + ((size_t)row * UNITS + (kb ^ (row & 7))) * 16) = b;
        }
        __syncthreads();

        f32x4 acc[6][2];
#pragma unroll
        for (int j = 0; j < 6; ++j)
#pragma unroll
            for (int r = 0; r < 2; ++r) acc[j][r] = (f32x4){0.f, 0.f, 0.f, 0.f};

#pragma unroll
        for (int ks = 0; ks < K / 32; ++ks) {
            bf16x8 a0 = {}, a1 = {};
            int row0 = bm + r16;
            int row1 = bm + 16 + r16;
            if (XF32) {
                const float* Xf = (const float*)Xv;
                if (row0 < n) {
                    const float* s0 = Xf + (size_t)row0 * K + ks * 32 + hi * 8;
                    float4 va = *(const float4*)s0, vb = *(const float4*)(s0 + 4);
                    unsigned short* ap = (unsigned short*)&a0;
                    ap[0] = f2bf(va.x); ap[1] = f2bf(va.y); ap[2] = f2bf(va.z); ap[3] = f2bf(va.w);
                    ap[4] = f2bf(vb.x); ap[5] = f2bf(vb.y); ap[6] = f2bf(vb.z); ap[7] = f2bf(vb.w);
                }
                if (row1 < n) {
                    const float* s1 = Xf + (size_t)row1 * K + ks * 32 + hi * 8;
                    float4 va = *(const float4*)s1, vb = *(const float4*)(s1 + 4);
                    unsigned short* ap = (unsigned short*)&a1;
                    ap[0] = f2bf(va.x); ap[1] = f2bf(va.y); ap[2] = f2bf(va.z); ap[3] = f2bf(va.w);
                    ap[4] = f2bf(vb.x); ap[5] = f2bf(vb.y); ap[6] = f2bf(vb.z); ap[7] = f2bf(vb.w);
                }
            } else {
                const unsigned short* Xb = (const unsigned short*)Xv;
                if (row0 < n) a0 = *(const bf16x8*)(Xb + (size_t)row0 * K + ks * 32 + hi * 8);
                if (row1 < n) a1 = *(const bf16x8*)(Xb + (size_t)row1 * K + ks * 32 + hi * 8);
            }
#pragma unroll
            for (int j = 0; j < 6; ++j) {
                int wl = j * 16 + r16;
                int kb = ks * 4 + hi;
                bf16x8 b = *(const bf16x8*)(smem + ((size_t)wl * UNITS + (kb ^ (wl & 7))) * 16);
                acc[j][0] = __builtin_amdgcn_mfma_f32_16x16x32_bf16(a0, b, acc[j][0], 0, 0, 0);
                acc[j][1] = __builtin_amdgcn_mfma_f32_16x16x32_bf16(a1, b, acc[j][1], 0, 0, 0);
            }
        }

        float atl[6], atr[6];
#pragma unroll
        for (int j = 0; j < 6; ++j) {
            int col = p * 96 + j * 16 + r16;
            atl[j] = attl[col];
            atr[j] = attr[col];
        }
#pragma unroll
        for (int j = 0; j < 6; ++j) {
            const int hj = (p * 96 + j * 16) >> 6;
#pragma unroll
            for (int r = 0; r < 2; ++r)
#pragma unroll
                for (int q = 0; q < 4; ++q) {
                    alp[hj][r][q] += acc[j][r][q] * atl[j];
                    arp[hj][r][q] += acc[j][r][q] * atr[j];
                }
        }
#pragma unroll
        for (int j = 0; j < 6; ++j)
#pragma unroll
            for (int r = 0; r < 2; ++r)
#pragma unroll
                for (int q = 0; q < 4; ++q) {
                    int row = bm + r * 16 + hi * 4 + q;
                    if (row < n)
                        Cbf[(size_t)row * HC + p * 96 + j * 16 + r16] = f2bf(acc[j][r][q]);
                }
        __syncthreads();
    }

#pragma unroll
    for (int h = 0; h < 3; ++h)
#pragma unroll
        for (int r = 0; r < 2; ++r)
#pragma unroll
            for (int q = 0; q < 4; ++q) {
#pragma unroll
                for (int off = 1; off < 16; off <<= 1) {
                    alp[h][r][q] += __shfl_xor(alp[h][r][q], off);
                    arp[h][r][q] += __shfl_xor(arp[h][r][q], off);
                }
            }
    if (r16 == 0) {
#pragma unroll
        for (int r = 0; r < 2; ++r)
#pragma unroll
            for (int q = 0; q < 4; ++q) {
                int row = bm + r * 16 + hi * 4 + q;
                if (row < n) {
#pragma unroll
                    for (int h = 0; h < 3; ++h) {
                        al[row * 3 + h] = alp[h][r][q];
                        ar[row * 3 + h] = arp[h][r][q];
                    }
                }
            }
    }
}

// ---------------- head GEMM (fp32): out[n,40] = B[n,192] @ Wo[40,192]^T + bo ----------------
// 64 rows x 40 cols per block (no wasted BN cols); 782 blocks (R9: 391-block
// 128x64 tile was occupancy-limited). Per-thread 2x5.

__global__ __launch_bounds__(256) void head_gemm(const float* __restrict__ X,
                                                 const float* __restrict__ Wo,
                                                 const float* __restrict__ bo,
                                                 float* __restrict__ C, int n) {
    __shared__ float Xs[16][64 + 4];
    __shared__ float Ws[16][40 + 2];
    int bm = blockIdx.x * 64;
    int tid = threadIdx.x;
    int tx = tid & 7;    // 8 col groups x 5
    int ty = tid >> 3;   // 32 row groups x 2
    float acc[2][5] = {};

    for (int k0 = 0; k0 < HC; k0 += 16) {
        {
            int row = tid >> 2;
            int ks = (tid & 3) * 4;
            int grow = bm + row;
            float4 v = make_float4(0.f, 0.f, 0.f, 0.f);
            if (grow < n) v = *(const float4*)(X + (size_t)grow * HC + k0 + ks);
            Xs[ks + 0][row] = v.x; Xs[ks + 1][row] = v.y;
            Xs[ks + 2][row] = v.z; Xs[ks + 3][row] = v.w;
        }
        if (tid < 160) {
            int rowm = tid >> 2;
            int ks = (tid & 3) * 4;
            float4 v = *(const float4*)(Wo + (size_t)rowm * HC + k0 + ks);
            Ws[ks + 0][rowm] = v.x; Ws[ks + 1][rowm] = v.y;
            Ws[ks + 2][rowm] = v.z; Ws[ks + 3][rowm] = v.w;
        }
        __syncthreads();
#pragma unroll
        for (int kk = 0; kk < 16; ++kk) {
            float x0 = Xs[kk][ty * 2 + 0];
            float x1 = Xs[kk][ty * 2 + 1];
            float w[5];
#pragma unroll
            for (int j = 0; j < 5; ++j) w[j] = Ws[kk][tx * 5 + j];
#pragma unroll
            for (int j = 0; j < 5; ++j) {
                acc[0][j] += x0 * w[j];
                acc[1][j] += x1 * w[j];
            }
        }
        __syncthreads();
    }
#pragma unroll
    for (int r = 0; r < 2; ++r) {
        int grow = bm + ty * 2 + r;
        if (grow >= n) continue;
#pragma unroll
        for (int j = 0; j < 5; ++j) {
            int gc = tx * 5 + j;
            C[(size_t)grow * NCLS + gc] = acc[r][j] + bo[gc];
        }
    }
}

// ---------------- single-pass fused softmax + gather: wave per node ----------------
// No max-subtract (|alpha| small, fp32-exp-safe; softmax identity). One edge
// pass: acc += e^alpha * h, s += e^alpha. s is replicated within each 16-lane
// head group (no reduction). Self-loop guarantees s > 0. Lanes >=48 retire.

template <bool RELU, bool OUT_BF16>
__global__ __launch_bounds__(256) void gatherw_kernel(const unsigned short* __restrict__ hfeat,
                                                      const float* __restrict__ al,
                                                      const float* __restrict__ ar,
                                                      const int* __restrict__ rowp,
                                                      const int* __restrict__ esrc,
                                                      const float* __restrict__ bias,
                                                      void* __restrict__ outv, int n) {
    int node = blockIdx.x * 4 + (threadIdx.x >> 6);
    if (node >= n) return;
    int lane = threadIdx.x & 63;
    if (lane >= 48) return;              // no cross-lane ops / barriers below
    int head = lane >> 4;
    int c4 = lane & 15;
    int e0 = rowp[node], e1 = rowp[node + 1];
    float arh = ar[node * 3 + head];
    const unsigned short* base = hfeat + (size_t)head * HIDC + c4 * 4;

    float4 acc = make_float4(0.f, 0.f, 0.f, 0.f);
    float s = 0.f;
    int e = e0;
    for (; e + 4 <= e1; e += 4) {
        int s0i = esrc[e + 0], s1i = esrc[e + 1], s2i = esrc[e + 2], s3i = esrc[e + 3];
        float w0 = __expf(lrelu(al[s0i * 3 + head] + arh));
        float w1 = __expf(lrelu(al[s1i * 3 + head] + arh));
        float w2 = __expf(lrelu(al[s2i * 3 + head] + arh));
        float w3 = __expf(lrelu(al[s3i * 3 + head] + arh));
        ushort4 u0 = *(const ushort4*)(base + (size_t)s0i * HC);
        ushort4 u1 = *(const ushort4*)(base + (size_t)s1i * HC);
        ushort4 u2 = *(const ushort4*)(base + (size_t)s2i * HC);
        ushort4 u3 = *(const ushort4*)(base + (size_t)s3i * HC);
        s += (w0 + w1) + (w2 + w3);
        acc.x += w0 * bf2f(u0.x) + w1 * bf2f(u1.x) + w2 * bf2f(u2.x) + w3 * bf2f(u3.x);
        acc.y += w0 * bf2f(u0.y) + w1 * bf2f(u1.y) + w2 * bf2f(u2.y) + w3 * bf2f(u3.y);
        acc.z += w0 * bf2f(u0.z) + w1 * bf2f(u1.z) + w2 * bf2f(u2.z) + w3 * bf2f(u3.z);
        acc.w += w0 * bf2f(u0.w) + w1 * bf2f(u1.w) + w2 * bf2f(u2.w) + w3 * bf2f(u3.w);
    }
    for (; e < e1; ++e) {
        int si = esrc[e];
        float w = __expf(lrelu(al[si * 3 + head] + arh));
        ushort4 u = *(const ushort4*)(base + (size_t)si * HC);
        s += w;
        acc.x += w * bf2f(u.x);
        acc.y += w * bf2f(u.y);
        acc.z += w * bf2f(u.z);
        acc.w += w * bf2f(u.w);
    }
    float rs = 1.f / (s + 1e-16f);
    const float4 bv = *(const float4*)(bias + lane * 4);
    float4 v;
    v.x = acc.x * rs + bv.x; v.y = acc.y * rs + bv.y;
    v.z = acc.z * rs + bv.z; v.w = acc.w * rs + bv.w;
    if (RELU) {
        v.x = fmaxf(v.x, 0.f); v.y = fmaxf(v.y, 0.f);
        v.z = fmaxf(v.z, 0.f); v.w = fmaxf(v.w, 0.f);
    }
    size_t idx = (size_t)node * HC + lane * 4;
    if (OUT_BF16) {
        ushort4 u;
        u.x = f2bf(v.x); u.y = f2bf(v.y); u.z = f2bf(v.z); u.w = f2bf(v.w);
        *(ushort4*)((unsigned short*)outv + idx) = u;
    } else {
        *(float4*)((float*)outv + idx) = v;
    }
}

// ---------------- launch ----------------

extern "C" void kernel_launch(void* const* d_in, const int* in_sizes, int n_in,
                              void* d_out, int out_size, void* d_ws, size_t ws_size,
                              hipStream_t stream) {
    const float* x     = (const float*)d_in[0];
    const int*   ei    = (const int*)d_in[1];
    const float* W1    = (const float*)d_in[2];
    const float* attl1 = (const float*)d_in[3];
    const float* attr1 = (const float*)d_in[4];
    const float* b1    = (const float*)d_in[5];
    const float* W2    = (const float*)d_in[6];
    const float* attl2 = (const float*)d_in[7];
    const float* attr2 = (const float*)d_in[8];
    const float* b2    = (const float*)d_in[9];
    const float* Wo    = (const float*)d_in[10];
    const float* bo    = (const float*)d_in[11];
    float* outp = (float*)d_out;

    const int n = NNODES;
    const int E_ = NEDGES;
    const int ET = E_ + n;

    char* ws = (char*)d_ws;
    size_t off = 0;
    auto take = [&](size_t bytes) {
        size_t p = off;
        off += (bytes + 255) & ~(size_t)255;
        return p;
    };
    float* A            = (float*)(ws + take((size_t)n * HC * 4));
    unsigned short* Abf = (unsigned short*)(ws + take((size_t)n * HC * 2));
    unsigned short* Bbf = (unsigned short*)(ws + take((size_t)n * HC * 2));
    float* al   = (float*)(ws + take((size_t)n * 3 * 4));
    float* ar   = (float*)(ws + take((size_t)n * 3 * 4));
    int* rowp   = (int*)(ws + take((size_t)(n + 1) * 4));
    int* deg    = (int*)(ws + take((size_t)n * 4));
    int* cursor = (int*)(ws + take((size_t)n * 4));
    int* esrc   = (int*)(ws + take((size_t)ET * 4));
    int* bsum   = (int*)(ws + take((size_t)SB * 4));
    int* boff   = (int*)(ws + take((size_t)SB * 4));
    (void)ws_size;

    hipMemsetAsync(deg, 0, (size_t)n * 4, stream);
    hipMemsetAsync(cursor, 0, (size_t)n * 4, stream);

    int eb = 256;
    int eg = (ET + eb - 1) / eb;
    hist_kernel<<<eg, eb, 0, stream>>>(ei, deg, E_, n);
    bsum_kernel<<<SB, 256, 0, stream>>>(deg, bsum, n);
    bscan_kernel<<<1, SB, 0, stream>>>(bsum, boff, rowp, n);
    scan_chunk_kernel<<<SB, 256, 0, stream>>>(deg, boff, rowp, n);
    scatter_kernel<<<eg, eb, 0, stream>>>(ei, rowp, cursor, esrc, E_, n);

    int mfma_grid = (n + 95) / 96;
    int nodeg4 = (n + 3) / 4;
    int headg = (n + 63) / 64;

    // layer 1
    gemm_mfma<128, true><<<mfma_grid, 192, 0, stream>>>(x, W1, attl1, attr1, Abf, al, ar, n);
    gatherw_kernel<true, true><<<nodeg4, 256, 0, stream>>>(Abf, al, ar, rowp, esrc, b1, Bbf, n);
    // layer 2
    gemm_mfma<192, false><<<mfma_grid, 192, 0, stream>>>(Bbf, W2, attl2, attr2, Abf, al, ar, n);
    gatherw_kernel<true, false><<<nodeg4, 256, 0, stream>>>(Abf, al, ar, rowp, esrc, b2, A, n);
    // output head
    head_gemm<<<headg, 256, 0, stream>>>(A, Wo, bo, outp, n);
}

// Round 11
// 222.287 us; speedup vs baseline: 4.1962x; 1.0523x over previous
//
#include <hip/hip_runtime.h>
#include <hip/hip_bf16.h>

// GAT 2-layer + linear head.
// Layer GEMMs: bf16 MFMA (fp32 accum), W pre-cast to bf16, epilogue fuses
// al/ar projection + bf16 feature write. Gather: single-pass unnormalized
// softmax (|alpha| small => fp32-exp-safe; exact identity).
// N=50000, E=400000 (+N self loops), IN_DIM=128, HEADS=3, HID=64 (HC=192), CLASSES=40.

#define NNODES 50000
#define NEDGES 400000
#define HC 192
#define NHEADS 3
#define HIDC 64
#define NCLS 40

#define SB 256
#define CHUNK 196

typedef __attribute__((ext_vector_type(8))) short bf16x8;
typedef __attribute__((ext_vector_type(4))) float f32x4;

__device__ __forceinline__ float lrelu(float a) { return a > 0.f ? a : 0.2f * a; }
__device__ __forceinline__ float bf2f(unsigned short u) {
    return __uint_as_float((unsigned)u << 16);
}
__device__ __forceinline__ unsigned short f2bf(float f) {
    __hip_bfloat16 b = __float2bfloat16(f);
    return *(unsigned short*)&b;
}

// ---------------- bf16 cast (weights only) ----------------

__global__ void cast_bf16_kernel(const float* __restrict__ src,
                                 unsigned short* __restrict__ dst, int count4) {
    int i = blockIdx.x * blockDim.x + threadIdx.x;
    int stride = gridDim.x * blockDim.x;
    for (; i < count4; i += stride) {
        float4 v = ((const float4*)src)[i];
        ushort4 u;
        u.x = f2bf(v.x); u.y = f2bf(v.y); u.z = f2bf(v.z); u.w = f2bf(v.w);
        ((ushort4*)dst)[i] = u;
    }
}

// ---------------- CSR build ----------------

__global__ void hist_kernel(const int* __restrict__ ei, int* __restrict__ deg,
                            int E_, int n) {
    int e = blockIdx.x * blockDim.x + threadIdx.x;
    int ET = E_ + n;
    if (e >= ET) return;
    int d = (e < E_) ? ei[E_ + e] : (e - E_);
    atomicAdd(&deg[d], 1);
}

__global__ __launch_bounds__(256) void bsum_kernel(const int* __restrict__ deg,
                                                   int* __restrict__ bsum, int n) {
    int b = blockIdx.x, t = threadIdx.x;
    int i = b * CHUNK + t;
    int v = (t < CHUNK && i < n) ? deg[i] : 0;
#pragma unroll
    for (int off = 32; off; off >>= 1) v += __shfl_xor(v, off);
    __shared__ int sh[4];
    if ((t & 63) == 0) sh[t >> 6] = v;
    __syncthreads();
    if (t == 0) bsum[b] = sh[0] + sh[1] + sh[2] + sh[3];
}

__global__ __launch_bounds__(256) void bscan_kernel(const int* __restrict__ bsum,
                                                    int* __restrict__ boff,
                                                    int* __restrict__ rowp, int n) {
    __shared__ int sh[SB];
    int t = threadIdx.x;
    int v = bsum[t];
    sh[t] = v;
    __syncthreads();
    for (int off = 1; off < SB; off <<= 1) {
        int u = (t >= off) ? sh[t - off] : 0;
        __syncthreads();
        sh[t] += u;
        __syncthreads();
    }
    boff[t] = sh[t] - v;
    if (t == SB - 1) rowp[n] = sh[t];
}

__global__ __launch_bounds__(256) void scan_chunk_kernel(const int* __restrict__ deg,
                                                         const int* __restrict__ boff,
                                                         int* __restrict__ rowp, int n) {
    __shared__ int sh[256];
    int b = blockIdx.x, t = threadIdx.x;
    int i = b * CHUNK + t;
    int v = (t < CHUNK && i < n) ? deg[i] : 0;
    sh[t] = v;
    __syncthreads();
    for (int off = 1; off < 256; off <<= 1) {
        int u = (t >= off) ? sh[t - off] : 0;
        __syncthreads();
        sh[t] += u;
        __syncthreads();
    }
    if (t < CHUNK && i < n) rowp[i] = boff[b] + sh[t] - v;
}

__global__ void scatter_kernel(const int* __restrict__ ei, const int* __restrict__ rowp,
                               int* __restrict__ cursor, int* __restrict__ esrc,
                               int E_, int n) {
    int e = blockIdx.x * blockDim.x + threadIdx.x;
    int ET = E_ + n;
    if (e >= ET) return;
    int s, d;
    if (e < E_) { s = ei[e]; d = ei[E_ + e]; }
    else        { s = e - E_; d = s; }
    int pos = atomicAdd(&cursor[d], 1);
    esrc[rowp[d] + pos] = s;
}

// ---------------- MFMA GEMM v2 + fused epilogue ----------------
// C[n,192] = X[n,K] @ Wbf[192,K]^T. 256 threads = 4 waves x 32 rows = 128
// rows/block, full 192-col width. W (pre-cast bf16) staged in 2 K-halves
// (<=40KB LDS -> 4 blocks/CU; R10: fp32-cvt-restaging at 3 waves/CU was the
// cost). Row pad (UNITS_H+1 units) -> 2-way LDS bank aliasing (free).
// Epilogue-only al/ar projection (not live through K loop).

template <int K, bool XF32>
__global__ __launch_bounds__(256) void gemm_mfma(const void* __restrict__ Xv,
                                                 const unsigned short* __restrict__ Wbf,
                                                 const float* __restrict__ attl,
                                                 const float* __restrict__ attr,
                                                 unsigned short* __restrict__ Cbf,
                                                 float* __restrict__ al,
                                                 float* __restrict__ ar, int n) {
    constexpr int UH = K / 16;              // 16B units per row per K-half
    __shared__ char smem[192 * (UH + 1) * 16];
    int tid = threadIdx.x;
    int wave = tid >> 6, lane = tid & 63;
    int r16 = lane & 15;
    int hi = lane >> 4;
    int bm = blockIdx.x * 128 + wave * 32;
    int row0 = bm + r16;
    int row1 = bm + 16 + r16;

    f32x4 acc[12][2];
#pragma unroll
    for (int j = 0; j < 12; ++j)
#pragma unroll
        for (int r = 0; r < 2; ++r) acc[j][r] = (f32x4){0.f, 0.f, 0.f, 0.f};

#pragma unroll
    for (int h = 0; h < 2; ++h) {
        if (h) __syncthreads();             // protect smem reuse
        // stage K-half h of all 192 W rows (bf16 copy)
        for (int u = tid; u < 192 * UH; u += 256) {
            int row = u / UH, kb = u % UH;
            uint4 v = *(const uint4*)(Wbf + (size_t)row * K + h * (K / 2) + kb * 8);
            *(uint4*)(smem + ((size_t)row * (UH + 1) + kb) * 16) = v;
        }
        __syncthreads();

#pragma unroll
        for (int ks = 0; ks < K / 64; ++ks) {
            int kofs = h * (K / 2) + ks * 32 + hi * 8;
            bf16x8 a0 = {}, a1 = {};
            if (XF32) {
                const float* Xf = (const float*)Xv;
                if (row0 < n) {
                    const float* s0 = Xf + (size_t)row0 * K + kofs;
                    float4 va = *(const float4*)s0, vb = *(const float4*)(s0 + 4);
                    unsigned short* ap = (unsigned short*)&a0;
                    ap[0] = f2bf(va.x); ap[1] = f2bf(va.y); ap[2] = f2bf(va.z); ap[3] = f2bf(va.w);
                    ap[4] = f2bf(vb.x); ap[5] = f2bf(vb.y); ap[6] = f2bf(vb.z); ap[7] = f2bf(vb.w);
                }
                if (row1 < n) {
                    const float* s1 = Xf + (size_t)row1 * K + kofs;
                    float4 va = *(const float4*)s1, vb = *(const float4*)(s1 + 4);
                    unsigned short* ap = (unsigned short*)&a1;
                    ap[0] = f2bf(va.x); ap[1] = f2bf(va.y); ap[2] = f2bf(va.z); ap[3] = f2bf(va.w);
                    ap[4] = f2bf(vb.x); ap[5] = f2bf(vb.y); ap[6] = f2bf(vb.z); ap[7] = f2bf(vb.w);
                }
            } else {
                const unsigned short* Xb = (const unsigned short*)Xv;
                if (row0 < n) a0 = *(const bf16x8*)(Xb + (size_t)row0 * K + kofs);
                if (row1 < n) a1 = *(const bf16x8*)(Xb + (size_t)row1 * K + kofs);
            }
            int kb = ks * 4 + hi;
#pragma unroll
            for (int j = 0; j < 12; ++j) {
                int wl = j * 16 + r16;
                bf16x8 b = *(const bf16x8*)(smem + ((size_t)wl * (UH + 1) + kb) * 16);
                acc[j][0] = __builtin_amdgcn_mfma_f32_16x16x32_bf16(a0, b, acc[j][0], 0, 0, 0);
                acc[j][1] = __builtin_amdgcn_mfma_f32_16x16x32_bf16(a1, b, acc[j][1], 0, 0, 0);
            }
        }
    }

    // epilogue: al/ar projection partials + bf16 feature write
    float alp[3][2][4] = {};
    float arp[3][2][4] = {};
#pragma unroll
    for (int j = 0; j < 12; ++j) {
        int col = j * 16 + r16;
        float atl = attl[col];
        float atr = attr[col];
        const int hj = j >> 2;              // head = col/64, compile-time
#pragma unroll
        for (int r = 0; r < 2; ++r)
#pragma unroll
            for (int q = 0; q < 4; ++q) {
                alp[hj][r][q] += acc[j][r][q] * atl;
                arp[hj][r][q] += acc[j][r][q] * atr;
            }
    }
#pragma unroll
    for (int j = 0; j < 12; ++j)
#pragma unroll
        for (int r = 0; r < 2; ++r)
#pragma unroll
            for (int q = 0; q < 4; ++q) {
                int row = bm + r * 16 + hi * 4 + q;
                if (row < n)
                    Cbf[(size_t)row * HC + j * 16 + r16] = f2bf(acc[j][r][q]);
            }
#pragma unroll
    for (int h = 0; h < 3; ++h)
#pragma unroll
        for (int r = 0; r < 2; ++r)
#pragma unroll
            for (int q = 0; q < 4; ++q) {
#pragma unroll
                for (int off = 1; off < 16; off <<= 1) {
                    alp[h][r][q] += __shfl_xor(alp[h][r][q], off);
                    arp[h][r][q] += __shfl_xor(arp[h][r][q], off);
                }
            }
    if (r16 == 0) {
#pragma unroll
        for (int r = 0; r < 2; ++r)
#pragma unroll
            for (int q = 0; q < 4; ++q) {
                int row = bm + r * 16 + hi * 4 + q;
                if (row < n) {
#pragma unroll
                    for (int h = 0; h < 3; ++h) {
                        al[row * 3 + h] = alp[h][r][q];
                        ar[row * 3 + h] = arp[h][r][q];
                    }
                }
            }
    }
}

// ---------------- head GEMM (fp32): out[n,40] = B[n,192] @ Wo[40,192]^T + bo ----------------

__global__ __launch_bounds__(256) void head_gemm(const float* __restrict__ X,
                                                 const float* __restrict__ Wo,
                                                 const float* __restrict__ bo,
                                                 float* __restrict__ C, int n) {
    __shared__ float Xs[16][64 + 4];
    __shared__ float Ws[16][40 + 2];
    int bm = blockIdx.x * 64;
    int tid = threadIdx.x;
    int tx = tid & 7;
    int ty = tid >> 3;
    float acc[2][5] = {};

    for (int k0 = 0; k0 < HC; k0 += 16) {
        {
            int row = tid >> 2;
            int ks = (tid & 3) * 4;
            int grow = bm + row;
            float4 v = make_float4(0.f, 0.f, 0.f, 0.f);
            if (grow < n) v = *(const float4*)(X + (size_t)grow * HC + k0 + ks);
            Xs[ks + 0][row] = v.x; Xs[ks + 1][row] = v.y;
            Xs[ks + 2][row] = v.z; Xs[ks + 3][row] = v.w;
        }
        if (tid < 160) {
            int rowm = tid >> 2;
            int ks = (tid & 3) * 4;
            float4 v = *(const float4*)(Wo + (size_t)rowm * HC + k0 + ks);
            Ws[ks + 0][rowm] = v.x; Ws[ks + 1][rowm] = v.y;
            Ws[ks + 2][rowm] = v.z; Ws[ks + 3][rowm] = v.w;
        }
        __syncthreads();
#pragma unroll
        for (int kk = 0; kk < 16; ++kk) {
            float x0 = Xs[kk][ty * 2 + 0];
            float x1 = Xs[kk][ty * 2 + 1];
            float w[5];
#pragma unroll
            for (int j = 0; j < 5; ++j) w[j] = Ws[kk][tx * 5 + j];
#pragma unroll
            for (int j = 0; j < 5; ++j) {
                acc[0][j] += x0 * w[j];
                acc[1][j] += x1 * w[j];
            }
        }
        __syncthreads();
    }
#pragma unroll
    for (int r = 0; r < 2; ++r) {
        int grow = bm + ty * 2 + r;
        if (grow >= n) continue;
#pragma unroll
        for (int j = 0; j < 5; ++j) {
            int gc = tx * 5 + j;
            C[(size_t)grow * NCLS + gc] = acc[r][j] + bo[gc];
        }
    }
}

// ---------------- single-pass fused softmax + gather: wave per node ----------------

template <bool RELU, bool OUT_BF16>
__global__ __launch_bounds__(256) void gatherw_kernel(const unsigned short* __restrict__ hfeat,
                                                      const float* __restrict__ al,
                                                      const float* __restrict__ ar,
                                                      const int* __restrict__ rowp,
                                                      const int* __restrict__ esrc,
                                                      const float* __restrict__ bias,
                                                      void* __restrict__ outv, int n) {
    int node = blockIdx.x * 4 + (threadIdx.x >> 6);
    if (node >= n) return;
    int lane = threadIdx.x & 63;
    if (lane >= 48) return;
    int head = lane >> 4;
    int c4 = lane & 15;
    int e0 = rowp[node], e1 = rowp[node + 1];
    float arh = ar[node * 3 + head];
    const unsigned short* base = hfeat + (size_t)head * HIDC + c4 * 4;

    float4 acc = make_float4(0.f, 0.f, 0.f, 0.f);
    float s = 0.f;
    int e = e0;
    for (; e + 4 <= e1; e += 4) {
        int s0i = esrc[e + 0], s1i = esrc[e + 1], s2i = esrc[e + 2], s3i = esrc[e + 3];
        float w0 = __expf(lrelu(al[s0i * 3 + head] + arh));
        float w1 = __expf(lrelu(al[s1i * 3 + head] + arh));
        float w2 = __expf(lrelu(al[s2i * 3 + head] + arh));
        float w3 = __expf(lrelu(al[s3i * 3 + head] + arh));
        ushort4 u0 = *(const ushort4*)(base + (size_t)s0i * HC);
        ushort4 u1 = *(const ushort4*)(base + (size_t)s1i * HC);
        ushort4 u2 = *(const ushort4*)(base + (size_t)s2i * HC);
        ushort4 u3 = *(const ushort4*)(base + (size_t)s3i * HC);
        s += (w0 + w1) + (w2 + w3);
        acc.x += w0 * bf2f(u0.x) + w1 * bf2f(u1.x) + w2 * bf2f(u2.x) + w3 * bf2f(u3.x);
        acc.y += w0 * bf2f(u0.y) + w1 * bf2f(u1.y) + w2 * bf2f(u2.y) + w3 * bf2f(u3.y);
        acc.z += w0 * bf2f(u0.z) + w1 * bf2f(u1.z) + w2 * bf2f(u2.z) + w3 * bf2f(u3.z);
        acc.w += w0 * bf2f(u0.w) + w1 * bf2f(u1.w) + w2 * bf2f(u2.w) + w3 * bf2f(u3.w);
    }
    for (; e < e1; ++e) {
        int si = esrc[e];
        float w = __expf(lrelu(al[si * 3 + head] + arh));
        ushort4 u = *(const ushort4*)(base + (size_t)si * HC);
        s += w;
        acc.x += w * bf2f(u.x);
        acc.y += w * bf2f(u.y);
        acc.z += w * bf2f(u.z);
        acc.w += w * bf2f(u.w);
    }
    float rs = 1.f / (s + 1e-16f);
    const float4 bv = *(const float4*)(bias + lane * 4);
    float4 v;
    v.x = acc.x * rs + bv.x; v.y = acc.y * rs + bv.y;
    v.z = acc.z * rs + bv.z; v.w = acc.w * rs + bv.w;
    if (RELU) {
        v.x = fmaxf(v.x, 0.f); v.y = fmaxf(v.y, 0.f);
        v.z = fmaxf(v.z, 0.f); v.w = fmaxf(v.w, 0.f);
    }
    size_t idx = (size_t)node * HC + lane * 4;
    if (OUT_BF16) {
        ushort4 u;
        u.x = f2bf(v.x); u.y = f2bf(v.y); u.z = f2bf(v.z); u.w = f2bf(v.w);
        *(ushort4*)((unsigned short*)outv + idx) = u;
    } else {
        *(float4*)((float*)outv + idx) = v;
    }
}

// ---------------- launch ----------------

extern "C" void kernel_launch(void* const* d_in, const int* in_sizes, int n_in,
                              void* d_out, int out_size, void* d_ws, size_t ws_size,
                              hipStream_t stream) {
    const float* x     = (const float*)d_in[0];
    const int*   ei    = (const int*)d_in[1];
    const float* W1    = (const float*)d_in[2];
    const float* attl1 = (const float*)d_in[3];
    const float* attr1 = (const float*)d_in[4];
    const float* b1    = (const float*)d_in[5];
    const float* W2    = (const float*)d_in[6];
    const float* attl2 = (const float*)d_in[7];
    const float* attr2 = (const float*)d_in[8];
    const float* b2    = (const float*)d_in[9];
    const float* Wo    = (const float*)d_in[10];
    const float* bo    = (const float*)d_in[11];
    float* outp = (float*)d_out;

    const int n = NNODES;
    const int E_ = NEDGES;
    const int ET = E_ + n;

    char* ws = (char*)d_ws;
    size_t off = 0;
    auto take = [&](size_t bytes) {
        size_t p = off;
        off += (bytes + 255) & ~(size_t)255;
        return p;
    };
    float* A            = (float*)(ws + take((size_t)n * HC * 4));
    unsigned short* Abf = (unsigned short*)(ws + take((size_t)n * HC * 2));
    unsigned short* Bbf = (unsigned short*)(ws + take((size_t)n * HC * 2));
    unsigned short* W1bf = (unsigned short*)(ws + take((size_t)HC * 128 * 2));
    unsigned short* W2bf = (unsigned short*)(ws + take((size_t)HC * HC * 2));
    float* al   = (float*)(ws + take((size_t)n * 3 * 4));
    float* ar   = (float*)(ws + take((size_t)n * 3 * 4));
    int* rowp   = (int*)(ws + take((size_t)(n + 1) * 4));
    int* deg    = (int*)(ws + take((size_t)n * 4));
    int* cursor = (int*)(ws + take((size_t)n * 4));
    int* esrc   = (int*)(ws + take((size_t)ET * 4));
    int* bsum   = (int*)(ws + take((size_t)SB * 4));
    int* boff   = (int*)(ws + take((size_t)SB * 4));
    (void)ws_size;

    hipMemsetAsync(deg, 0, (size_t)n * 4, stream);
    hipMemsetAsync(cursor, 0, (size_t)n * 4, stream);

    // W pre-casts (bf16)
    cast_bf16_kernel<<<(HC * 128 / 4 + 255) / 256, 256, 0, stream>>>(W1, W1bf, HC * 128 / 4);
    cast_bf16_kernel<<<(HC * HC / 4 + 255) / 256, 256, 0, stream>>>(W2, W2bf, HC * HC / 4);

    int eb = 256;
    int eg = (ET + eb - 1) / eb;
    hist_kernel<<<eg, eb, 0, stream>>>(ei, deg, E_, n);
    bsum_kernel<<<SB, 256, 0, stream>>>(deg, bsum, n);
    bscan_kernel<<<1, SB, 0, stream>>>(bsum, boff, rowp, n);
    scan_chunk_kernel<<<SB, 256, 0, stream>>>(deg, boff, rowp, n);
    scatter_kernel<<<eg, eb, 0, stream>>>(ei, rowp, cursor, esrc, E_, n);

    int mfma_grid = (n + 127) / 128;
    int nodeg4 = (n + 3) / 4;
    int headg = (n + 63) / 64;

    // layer 1
    gemm_mfma<128, true><<<mfma_grid, 256, 0, stream>>>(x, W1bf, attl1, attr1, Abf, al, ar, n);
    gatherw_kernel<true, true><<<nodeg4, 256, 0, stream>>>(Abf, al, ar, rowp, esrc, b1, Bbf, n);
    // layer 2
    gemm_mfma<192, false><<<mfma_grid, 256, 0, stream>>>(Bbf, W2bf, attl2, attr2, Abf, al, ar, n);
    gatherw_kernel<true, false><<<nodeg4, 256, 0, stream>>>(Abf, al, ar, rowp, esrc, b2, A, n);
    // output head
    head_gemm<<<headg, 256, 0, stream>>>(A, Wo, bo, outp, n);
}